// Round 8
// baseline (112.276 us; speedup 1.0000x reference)
//
#include <hip/hip_runtime.h>
#include <hip/hip_bf16.h>
#include <stdint.h>

typedef __attribute__((ext_vector_type(8))) short bf16x8;
typedef __attribute__((ext_vector_type(4))) short short4v;
typedef __attribute__((ext_vector_type(4))) float f32x4;
typedef __attribute__((ext_vector_type(16))) float f32x16;
typedef __attribute__((ext_vector_type(4))) unsigned uint4v;

#define LDS3(p) ((__attribute__((address_space(3))) void*)(p))
#define GLB1(p) ((const __attribute__((address_space(1))) void*)(p))

constexpr int Bc = 4;
constexpr int Cc = 256;   // channels (= d_v)
constexpr int Nn = 4096;  // H*W
constexpr int Dq = 32;    // C/8 (= d_qk)
constexpr float L2E = 1.4426950408889634f;

__device__ __forceinline__ short f2b(float x) {
  union { float f; uint32_t u; } v; v.f = x;
  uint32_t r = (v.u + 0x7fffu + ((v.u >> 16) & 1u)) >> 16;  // RNE
  return (short)(r & 0xffffu);
}
__device__ __forceinline__ float b2f(short s) {
  union { uint32_t u; float f; } v; v.u = ((uint32_t)(uint16_t)s) << 16;
  return v.f;
}
__device__ __forceinline__ unsigned fb(float x) {
  union { float f; unsigned u; } v; v.f = x; return v.u;
}

// ---------------------------------------------------------------------------
// Kernel 1: transpose-convert f1/f2 [B][C][N] f32 -> [B][N][C] bf16
// ---------------------------------------------------------------------------
__global__ __launch_bounds__(256) void prep_transpose(
    const float* __restrict__ f1, const float* __restrict__ f2,
    short* __restrict__ f1T, short* __restrict__ f2T) {
  __shared__ float tile[64][65];
  const int bx = blockIdx.x;
  const int which = bx >> 10;          // 0: f1, 1: f2
  const int rem = bx & 1023;
  const int b = rem >> 8;
  const int cb = (rem >> 6) & 3;
  const int nb = rem & 63;
  const float* src = which ? f2 : f1;
  short* dst = which ? f2T : f1T;
  const int c0 = cb * 64, n0 = nb * 64;
  const int tid = threadIdx.x;
  const int lane = tid & 63;
  const int row4 = tid >> 6;
#pragma unroll
  for (int i = 0; i < 16; ++i) {
    const int cl = row4 + i * 4;
    tile[cl][lane] = src[(size_t)(b * Cc + c0 + cl) * Nn + n0 + lane];
  }
  __syncthreads();
#pragma unroll
  for (int i = 0; i < 16; ++i) {
    const int nl = row4 + i * 4;
    dst[(size_t)(b * Nn + n0 + nl) * Cc + c0 + lane] = f2b(tile[lane][nl]);
  }
}

// ---------------------------------------------------------------------------
// Kernel 2: convert weights f32 -> bf16 (layouts preserved: [out][in])
// ---------------------------------------------------------------------------
__global__ __launch_bounds__(256) void prep_weights(
    const float* __restrict__ Wq, const float* __restrict__ Wk,
    const float* __restrict__ Wv, short* __restrict__ Wq_b,
    short* __restrict__ Wk_b, short* __restrict__ Wv_b) {
  const int base = (blockIdx.x * 256 + threadIdx.x) * 4;
#pragma unroll
  for (int j = 0; j < 4; ++j) {
    const int idx = base + j;
    if (idx < 8192) Wq_b[idx] = f2b(Wq[idx]);
    else if (idx < 16384) Wk_b[idx - 8192] = f2b(Wk[idx - 8192]);
    else if (idx < 16384 + 65536) Wv_b[idx - 16384] = f2b(Wv[idx - 16384]);
  }
}

// ---------------------------------------------------------------------------
// Kernel 3: projections via MFMA (unchanged, known-good).
// ---------------------------------------------------------------------------
__global__ __launch_bounds__(256) void proj_qkv(
    const short* __restrict__ f1T, const short* __restrict__ f2T,
    const short* __restrict__ Wq_b, const float* __restrict__ bq,
    const short* __restrict__ Wk_b, const float* __restrict__ bk,
    const short* __restrict__ Wv_b, const float* __restrict__ bv,
    short* __restrict__ q_ws, short* __restrict__ k_ws,
    short* __restrict__ v_ws) {
  const int bx = blockIdx.x;
  const int b = bx >> 6;
  const int n0 = (bx & 63) * 64;
  const int tid = threadIdx.x;
  const int w = tid >> 6;
  const int lane = tid & 63;
  const int l16 = lane & 15;
  const int g = lane >> 4;

#pragma unroll
  for (int qk = 0; qk < 2; ++qk) {
    const short* X = qk ? f2T : f1T;
    const short* Wm = qk ? Wk_b : Wq_b;
    const float* bias_p = qk ? bk : bq;
    short* outp = qk ? k_ws : q_ws;
    f32x4 accq[2] = {(f32x4){0.f, 0.f, 0.f, 0.f}, (f32x4){0.f, 0.f, 0.f, 0.f}};
#pragma unroll
    for (int kc = 0; kc < 8; ++kc) {
      const bf16x8 a = *(const bf16x8*)&X[(size_t)(b * Nn + n0 + w * 16 + l16) * Cc + kc * 32 + g * 8];
#pragma unroll
      for (int ob = 0; ob < 2; ++ob) {
        const bf16x8 bb = *(const bf16x8*)&Wm[(ob * 16 + l16) * Cc + kc * 32 + g * 8];
        accq[ob] = __builtin_amdgcn_mfma_f32_16x16x32_bf16(a, bb, accq[ob], 0, 0, 0);
      }
    }
#pragma unroll
    for (int ob = 0; ob < 2; ++ob) {
      const float bias = bias_p[ob * 16 + l16];
#pragma unroll
      for (int r = 0; r < 4; ++r) {
        const int n = n0 + w * 16 + g * 4 + r;
        outp[(size_t)(b * Nn + n) * Dq + ob * 16 + l16] = f2b(accq[ob][r] + bias);
      }
    }
  }

  {
    f32x4 acc[4][4];
#pragma unroll
    for (int ci = 0; ci < 4; ++ci)
#pragma unroll
      for (int nb = 0; nb < 4; ++nb) acc[ci][nb] = (f32x4){0.f, 0.f, 0.f, 0.f};
#pragma unroll
    for (int kc = 0; kc < 8; ++kc) {
      bf16x8 bfr[4];
#pragma unroll
      for (int nb = 0; nb < 4; ++nb)
        bfr[nb] = *(const bf16x8*)&f2T[(size_t)(b * Nn + n0 + nb * 16 + l16) * Cc + kc * 32 + g * 8];
#pragma unroll
      for (int ci = 0; ci < 4; ++ci) {
        const bf16x8 afr = *(const bf16x8*)&Wv_b[((w * 4 + ci) * 16 + l16) * Cc + kc * 32 + g * 8];
#pragma unroll
        for (int nb = 0; nb < 4; ++nb)
          acc[ci][nb] = __builtin_amdgcn_mfma_f32_16x16x32_bf16(afr, bfr[nb], acc[ci][nb], 0, 0, 0);
      }
    }
#pragma unroll
    for (int ci = 0; ci < 4; ++ci) {
#pragma unroll
      for (int r = 0; r < 4; ++r) {
        const int c = (w * 4 + ci) * 16 + g * 4 + r;
        const float bias = bv[c];
#pragma unroll
        for (int nb = 0; nb < 4; ++nb) {
          const int n = n0 + nb * 16 + l16;
          v_ws[(size_t)(b * Cc + c) * Nn + n] = f2b(acc[ci][nb][r] + bias);
        }
      }
    }
  }
}

// ---------------------------------------------------------------------------
// Kernel 4: flash attention, 32x32 MFMA, in-register P with rho-permuted K
// rows (verified round 7), now SKEWED 1-tile pipeline (T15):
//   per iter: QK(t+1) -> softmax(t+1)->pu_next [VALU]  ||  PV(t) [MFMA+LDS]
//   -> deferred acc rescale -> vmcnt(0)+barrier -> stage(t+2).
// NT=32 (LDS 32KB, regs fit <=256 with doubled pu state). Tree reductions.
// setprio(1) around PV. Defer-max THR=8. 1 barrier/tile.
// Epilogue: per-wave LDS transpose (4 phases) -> Opart [ks][b][c][m] + (m,l).
// ---------------------------------------------------------------------------
constexpr int NT = 32;
constexpr int VBUF = 256 * NT * 2;   // 16384 B per buffer ([c][4 granules])
constexpr int SBYTES = 2 * VBUF;     // 32768

template <int KS>
__global__ __launch_bounds__(256, 2) void attn_kernel(
    const short* __restrict__ q_ws, const short* __restrict__ k_ws,
    const short* __restrict__ v_ws, short* __restrict__ Opart,
    float* __restrict__ mlm, short* __restrict__ mll) {
  constexpr int KSPAN = Nn / KS;
  constexpr int NTILES = KSPAN / NT;
  __shared__ __align__(16) char smem[SBYTES];
  const int bx = blockIdx.x;
  const int swz = (bx & 7) * (16 * KS) + (bx >> 3);  // XCD-bijective
  const int ks = swz >> 7;
  const int rem = swz & 127;
  const int b = rem >> 5;
  const int m0 = (rem & 31) * 128;
  const int n0 = ks * KSPAN;
  const int tid = threadIdx.x;
  const int w = tid >> 6;
  const int lane = tid & 63;
  const int l31 = lane & 31;
  const int h = lane >> 5;

  // Q B-frags (persist): col m = m0 + w*32 + l31, k = s*16 + 8h + j
  const short* qbase = q_ws + (size_t)(b * Nn + m0 + w * 32 + l31) * Dq + h * 8;
  const bf16x8 qf0 = *(const bf16x8*)(qbase);
  const bf16x8 qf1 = *(const bf16x8*)(qbase + 16);

  // K A-frags at permuted row rho(l31) = swap bits 2<->3 (round-7 verified)
  const int kswap = (l31 & 0x13) | ((l31 & 4) << 1) | ((l31 & 8) >> 1);
  const short* kptr = k_ws + (size_t)(b * Nn + n0 + kswap) * Dq + h * 8;

  // V stage: granule (c = j*64 + tid>>2, slot = tid&3); source pre-swizzled
  // (slot ^= c&3) so the linear LDS-DMA lands the swizzled image.
  const int cth = tid >> 2;
  const int koff = 8 * ((tid & 3) ^ (cth & 3));
  const short* vsrc[4];
#pragma unroll
  for (int j = 0; j < 4; ++j)
    vsrc[j] = v_ws + (size_t)(b * Cc + j * 64 + cth) * Nn + n0 + koff;

  f32x16 acc[8] = {};  // O[m-pattern reg][c = cb*32 + l31]
  float mrun = -INFINITY, lrun = 0.f;

  // ---- prologue: stage(0), K(0), barrier, QK(0), softmax(0), stage(1)
#pragma unroll
  for (int j = 0; j < 4; ++j) {
    char* ldst = &smem[(j * 256 + tid) * 16];
    __builtin_amdgcn_global_load_lds(GLB1(vsrc[j]), LDS3(ldst), 16, 0, 0);
    vsrc[j] += NT;
  }
  bf16x8 kfa = *(const bf16x8*)(kptr);
  bf16x8 kfb = *(const bf16x8*)(kptr + 16);
  kptr += NT * Dq;
  asm volatile("s_waitcnt vmcnt(0)" ::: "memory");
  __syncthreads();

  const f32x16 Z = {};
  unsigned puC[8], puN[8];

  // softmax(0) from QK(0)
  {
    f32x16 sa = __builtin_amdgcn_mfma_f32_32x32x16_bf16(kfa, qf0, Z, 0, 0, 0);
    sa = __builtin_amdgcn_mfma_f32_32x32x16_bf16(kfb, qf1, sa, 0, 0, 0);
    kfa = *(const bf16x8*)(kptr);               // K(1)
    kfb = *(const bf16x8*)(kptr + 16);
    kptr += NT * Dq;
    float t8[8], t4[4];
#pragma unroll
    for (int i = 0; i < 8; ++i) t8[i] = fmaxf(sa[i], sa[i + 8]);
#pragma unroll
    for (int i = 0; i < 4; ++i) t4[i] = fmaxf(t8[i], t8[i + 4]);
    float tmax = fmaxf(fmaxf(t4[0], t4[2]), fmaxf(t4[1], t4[3]));
    tmax = fmaxf(tmax, __shfl_xor(tmax, 32));
    mrun = tmax;
    const float nml = -mrun * L2E;
    float p[16];
#pragma unroll
    for (int r = 0; r < 16; ++r) p[r] = exp2f(fmaf(sa[r], L2E, nml));
#pragma unroll
    for (int q = 0; q < 8; ++q)
      puC[q] = __builtin_amdgcn_perm(fb(p[2 * q + 1]), fb(p[2 * q]), 0x07060302u);
    float s8[8], s4[4];
#pragma unroll
    for (int i = 0; i < 8; ++i) s8[i] = p[i] + p[i + 8];
#pragma unroll
    for (int i = 0; i < 4; ++i) s4[i] = s8[i] + s8[i + 4];
    float psum = (s4[0] + s4[2]) + (s4[1] + s4[3]);
    psum += __shfl_xor(psum, 32);
    lrun = psum;
  }
  // stage(1) -> buf1
#pragma unroll
  for (int j = 0; j < 4; ++j) {
    char* ldst = &smem[VBUF + (j * 256 + tid) * 16];
    __builtin_amdgcn_global_load_lds(GLB1(vsrc[j]), LDS3(ldst), 16, 0, 0);
    vsrc[j] += NT;
  }

  // ---- main loop, skewed
#pragma unroll 2
  for (int t = 0; t < NTILES; ++t) {
    const int buf = t & 1;
    bool resc = false;
    float sv[16];
    if (t + 1 < NTILES) {
      // QK(t+1)
      f32x16 sa = __builtin_amdgcn_mfma_f32_32x32x16_bf16(kfa, qf0, Z, 0, 0, 0);
      sa = __builtin_amdgcn_mfma_f32_32x32x16_bf16(kfb, qf1, sa, 0, 0, 0);
      if (t + 2 < NTILES) {
        kfa = *(const bf16x8*)(kptr);           // K(t+2)
        kfb = *(const bf16x8*)(kptr + 16);
        kptr += NT * Dq;
      }
      // softmax(t+1) -> puN (overlaps PV(t) below in the scheduler)
      float t8[8], t4[4];
#pragma unroll
      for (int i = 0; i < 8; ++i) t8[i] = fmaxf(sa[i], sa[i + 8]);
#pragma unroll
      for (int i = 0; i < 4; ++i) t4[i] = fmaxf(t8[i], t8[i + 4]);
      float tmax = fmaxf(fmaxf(t4[0], t4[2]), fmaxf(t4[1], t4[3]));
      tmax = fmaxf(tmax, __shfl_xor(tmax, 32));
      resc = __any(tmax > mrun + 8.f);
      if (resc) {
        const float mnew = fmaxf(mrun, tmax);
        const float scl = exp2f((mrun - mnew) * L2E);
#pragma unroll
        for (int r = 0; r < 16; ++r)
          sv[r] = __shfl(scl, (r & 3) + 8 * (r >> 2) + 4 * h);
        lrun *= scl;
        mrun = mnew;
      }
      const float nml = -mrun * L2E;
      float p[16];
#pragma unroll
      for (int r = 0; r < 16; ++r) p[r] = exp2f(fmaf(sa[r], L2E, nml));
#pragma unroll
      for (int q = 0; q < 8; ++q)
        puN[q] = __builtin_amdgcn_perm(fb(p[2 * q + 1]), fb(p[2 * q]), 0x07060302u);
      float s8[8], s4[4];
#pragma unroll
      for (int i = 0; i < 8; ++i) s8[i] = p[i] + p[i + 8];
#pragma unroll
      for (int i = 0; i < 4; ++i) s4[i] = s8[i] + s8[i + 4];
      float psum = (s4[0] + s4[2]) + (s4[1] + s4[3]);
      psum += __shfl_xor(psum, 32);
      lrun += psum;
    }

    // ---- PV(t): A = puC frags, B = V[k16][c32] from swizzled LDS buf
    __builtin_amdgcn_s_setprio(1);
    const int sb = buf * VBUF;
#pragma unroll
    for (int f = 0; f < 2; ++f) {     // kstep: keys 16f .. 16f+15
      const uint4v au = {puC[4 * f], puC[4 * f + 1], puC[4 * f + 2], puC[4 * f + 3]};
      const bf16x8 A = __builtin_bit_cast(bf16x8, au);
      const char* vbase =
          &smem[sb + l31 * 64 + ((((f << 1) + h) ^ (l31 & 3)) << 4)];
#pragma unroll
      for (int cb = 0; cb < 8; ++cb) {
        const bf16x8 vB = *(const bf16x8*)(vbase + cb * 2048);
        acc[cb] = __builtin_amdgcn_mfma_f32_32x32x16_bf16(A, vB, acc[cb], 0, 0, 0);
      }
    }
    __builtin_amdgcn_s_setprio(0);

    if (t + 1 < NTILES) {
      if (resc) {   // deferred rescale (exact: applies to all tiles <= t)
#pragma unroll
        for (int cb = 0; cb < 8; ++cb)
#pragma unroll
          for (int r = 0; r < 16; ++r) acc[cb][r] *= sv[r];
      }
      asm volatile("s_waitcnt vmcnt(0)" ::: "memory");  // stage(t+1), K(t+2)
      __syncthreads();
      if (t + 2 < NTILES) {
#pragma unroll
        for (int j = 0; j < 4; ++j) {   // stage(t+2) -> buf just freed
          char* ldst = &smem[buf * VBUF + (j * 256 + tid) * 16];
          __builtin_amdgcn_global_load_lds(GLB1(vsrc[j]), LDS3(ldst), 16, 0, 0);
          vsrc[j] += NT;
        }
      }
#pragma unroll
      for (int q = 0; q < 8; ++q) puC[q] = puN[q];
    }
  }

  // ---- epilogue: (m,l) + per-wave LDS transpose -> Opart [ks][b][c][m]
  __syncthreads();  // all PV done; smem reusable as transpose strips
  if (h == 0) {
    const int m = m0 + w * 32 + l31;
    mlm[(size_t)(ks * Bc + b) * Nn + m] = mrun;
    mll[(size_t)(ks * Bc + b) * Nn + m] = f2b(lrun);
  }
  char* strip = smem + w * 5120;  // [64 c][80 B] per wave, private
#pragma unroll
  for (int ph = 0; ph < 4; ++ph) {
#pragma unroll
    for (int cb2 = 0; cb2 < 2; ++cb2) {
      const int cb = ph * 2 + cb2;
      const int cs = cb2 * 32 + l31;
#pragma unroll
      for (int q = 0; q < 8; ++q) {   // m-pairs: regs (2q, 2q+1)
        const int mloc = ((2 * q) & 3) + 8 * (q >> 1) + 4 * h;
        const unsigned pv = __builtin_amdgcn_perm(
            fb(acc[cb][2 * q + 1]), fb(acc[cb][2 * q]), 0x07060302u);
        *(unsigned*)(strip + cs * 80 + mloc * 2) = pv;
      }
    }
    asm volatile("s_waitcnt lgkmcnt(0)" ::: "memory");
#pragma unroll
    for (int i = 0; i < 4; ++i) {
      const int gi = i * 64 + lane;
      const int cs = gi >> 2, gq = gi & 3;
      const uint4v vv = *(const uint4v*)(strip + cs * 80 + gq * 16);
      const int cg = ph * 64 + cs;
      const size_t off =
          ((size_t)(ks * Bc + b) * Cc + cg) * Nn + m0 + w * 32 + gq * 8;
      *(uint4v*)&Opart[off] = vv;
    }
    asm volatile("s_waitcnt lgkmcnt(0)" ::: "memory");
  }
}

// ---------------------------------------------------------------------------
// Kernel 5: combine KS key-splits + residual (pure streaming, no transpose).
// ---------------------------------------------------------------------------
template <int KS>
__global__ __launch_bounds__(256) void combine_kernel(
    const short* __restrict__ Opart, const float* __restrict__ mlm,
    const short* __restrict__ mll, const float* __restrict__ feat1,
    const float* __restrict__ gamma_p, float* __restrict__ out) {
  __shared__ float aLDS[KS][64];
  const int bx = blockIdx.x;       // b*64 + mrange
  const int b = bx >> 6;
  const int m0 = (bx & 63) * 64;
  const int tid = threadIdx.x;
  if (tid < 64) {
    const int m = m0 + tid;
    float mm[KS], ll[KS], ms = -INFINITY;
#pragma unroll
    for (int ks = 0; ks < KS; ++ks) {
      mm[ks] = mlm[(size_t)(ks * Bc + b) * Nn + m];
      ll[ks] = b2f(mll[(size_t)(ks * Bc + b) * Nn + m]);
      ms = fmaxf(ms, mm[ks]);
    }
    float es[KS], lsum = 0.f;
#pragma unroll
    for (int ks = 0; ks < KS; ++ks) {
      es[ks] = exp2f((mm[ks] - ms) * L2E);
      lsum += ll[ks] * es[ks];
    }
    const float inv = 1.f / lsum;
#pragma unroll
    for (int ks = 0; ks < KS; ++ks) aLDS[ks][tid] = es[ks] * inv;
  }
  __syncthreads();
  const int mg = tid & 7;          // m-granule (8 m's)
  const int cb = tid >> 3;         // 0..31
  float aks[KS][8];
#pragma unroll
  for (int ks = 0; ks < KS; ++ks)
#pragma unroll
    for (int j = 0; j < 8; ++j) aks[ks][j] = aLDS[ks][mg * 8 + j];
  const float gam = gamma_p[0];
#pragma unroll 2
  for (int i = 0; i < 8; ++i) {
    const int c = cb + i * 32;
    float v[8] = {0.f, 0.f, 0.f, 0.f, 0.f, 0.f, 0.f, 0.f};
#pragma unroll
    for (int ks = 0; ks < KS; ++ks) {
      const bf16x8 ov = *(const bf16x8*)
          &Opart[((size_t)(ks * Bc + b) * Cc + c) * Nn + m0 + mg * 8];
#pragma unroll
      for (int j = 0; j < 8; ++j) v[j] += b2f(ov[j]) * aks[ks][j];
    }
    const size_t base = ((size_t)(b * Cc + c)) * Nn + m0 + mg * 8;
    const f32x4 fa = *(const f32x4*)&feat1[base];
    const f32x4 fbv = *(const f32x4*)&feat1[base + 4];
    f32x4 o0, o1;
#pragma unroll
    for (int j = 0; j < 4; ++j) {
      o0[j] = gam * v[j] + fa[j];
      o1[j] = gam * v[4 + j] + fbv[j];
    }
    *(f32x4*)&out[base] = o0;
    *(f32x4*)&out[base + 4] = o1;
  }
}

// ---------------------------------------------------------------------------
// Launch
// ---------------------------------------------------------------------------
extern "C" void kernel_launch(void* const* d_in, const int* in_sizes, int n_in,
                              void* d_out, int out_size, void* d_ws,
                              size_t ws_size, hipStream_t stream) {
  const float* feat1 = (const float*)d_in[0];
  const float* feat2 = (const float*)d_in[1];
  const float* Wq = (const float*)d_in[2];
  const float* bq = (const float*)d_in[3];
  const float* Wk = (const float*)d_in[4];
  const float* bk = (const float*)d_in[5];
  const float* Wv = (const float*)d_in[6];
  const float* bv = (const float*)d_in[7];
  const float* gamma = (const float*)d_in[8];
  float* out = (float*)d_out;
  char* ws = (char*)d_ws;

  const size_t need4 = 44433408;  // proven ws >= 44466176 (round-5 KS=2 ran)
  if (ws_size >= need4) {
    // KS=4 layout. f1T/f2T/W overlay Opart (dead before attn writes it).
    short* Opart = (short*)(ws + 0);          // 32 MiB [4][4][256][4096] bf16
    short* f1T  = (short*)(ws + 0);           //  8 MiB (overlay)
    short* f2T  = (short*)(ws + 8388608);     //  8 MiB (overlay)
    short* Wq_b = (short*)(ws + 16777216);    // 16 KiB (overlay)
    short* Wk_b = (short*)(ws + 16793600);
    short* Wv_b = (short*)(ws + 16809984);    // 128 KiB (overlay)
    short* q_ws = (short*)(ws + 33554432);    // 1 MiB
    short* k_ws = (short*)(ws + 34603008);    // 1 MiB
    short* v_ws = (short*)(ws + 35651584);    // 8 MiB
    float* mlm  = (float*)(ws + 44040192);    // 256 KiB f32
    short* mll  = (short*)(ws + 44302336);    // 128 KiB bf16

    prep_transpose<<<2048, 256, 0, stream>>>(feat1, feat2, f1T, f2T);
    prep_weights<<<80, 256, 0, stream>>>(Wq, Wk, Wv, Wq_b, Wk_b, Wv_b);
    proj_qkv<<<256, 256, 0, stream>>>(f1T, f2T, Wq_b, bq, Wk_b, bk, Wv_b, bv,
                                      q_ws, k_ws, v_ws);
    attn_kernel<4><<<512, 256, 0, stream>>>(q_ws, k_ws, v_ws, Opart, mlm, mll);
    combine_kernel<4><<<256, 256, 0, stream>>>(Opart, mlm, mll, feat1, gamma,
                                               out);
  } else {
    // KS=2 fallback (~27.6 MiB).
    short* Opart = (short*)(ws + 0);          // 16 MiB
    short* f1T  = (short*)(ws + 0);           // overlay
    short* f2T  = (short*)(ws + 8388608);     // overlay
    short* Wq_b = (short*)(ws + 16777216);
    short* Wk_b = (short*)(ws + 16793600);
    short* Wv_b = (short*)(ws + 16809984);
    short* q_ws = (short*)(ws + 16941056);
    short* k_ws = (short*)(ws + 17989632);
    short* v_ws = (short*)(ws + 19038208);
    float* mlm  = (float*)(ws + 27426816);
    short* mll  = (short*)(ws + 27557888);

    prep_transpose<<<2048, 256, 0, stream>>>(feat1, feat2, f1T, f2T);
    prep_weights<<<80, 256, 0, stream>>>(Wq, Wk, Wv, Wq_b, Wk_b, Wv_b);
    proj_qkv<<<256, 256, 0, stream>>>(f1T, f2T, Wq_b, bq, Wk_b, bk, Wv_b, bv,
                                      q_ws, k_ws, v_ws);
    attn_kernel<2><<<256, 256, 0, stream>>>(q_ws, k_ws, v_ws, Opart, mlm, mll);
    combine_kernel<2><<<256, 256, 0, stream>>>(Opart, mlm, mll, feat1, gamma,
                                               out);
  }
}

// Round 9
// 98.779 us; speedup vs baseline: 1.1366x; 1.1366x over previous
//
#include <hip/hip_runtime.h>
#include <hip/hip_bf16.h>
#include <stdint.h>

typedef __attribute__((ext_vector_type(8))) short bf16x8;
typedef __attribute__((ext_vector_type(4))) short short4v;
typedef __attribute__((ext_vector_type(4))) float f32x4;
typedef __attribute__((ext_vector_type(16))) float f32x16;
typedef __attribute__((ext_vector_type(4))) unsigned uint4v;

#define LDS3(p) ((__attribute__((address_space(3))) void*)(p))
#define GLB1(p) ((const __attribute__((address_space(1))) void*)(p))

constexpr int Bc = 4;
constexpr int Cc = 256;   // channels (= d_v)
constexpr int Nn = 4096;  // H*W
constexpr int Dq = 32;    // C/8 (= d_qk)
constexpr float L2E = 1.4426950408889634f;

__device__ __forceinline__ short f2b(float x) {
  union { float f; uint32_t u; } v; v.f = x;
  uint32_t r = (v.u + 0x7fffu + ((v.u >> 16) & 1u)) >> 16;  // RNE
  return (short)(r & 0xffffu);
}
__device__ __forceinline__ float b2f(short s) {
  union { uint32_t u; float f; } v; v.u = ((uint32_t)(uint16_t)s) << 16;
  return v.f;
}
__device__ __forceinline__ unsigned fb(float x) {
  union { float f; unsigned u; } v; v.f = x; return v.u;
}

// ---------------------------------------------------------------------------
// Kernel 1: convert weights f32 -> bf16 (layouts preserved: [out][in])
// ---------------------------------------------------------------------------
__global__ __launch_bounds__(256) void prep_weights(
    const float* __restrict__ Wq, const float* __restrict__ Wk,
    const float* __restrict__ Wv, short* __restrict__ Wq_b,
    short* __restrict__ Wk_b, short* __restrict__ Wv_b) {
  const int base = (blockIdx.x * 256 + threadIdx.x) * 4;
#pragma unroll
  for (int j = 0; j < 4; ++j) {
    const int idx = base + j;
    if (idx < 8192) Wq_b[idx] = f2b(Wq[idx]);
    else if (idx < 16384) Wk_b[idx - 8192] = f2b(Wk[idx - 8192]);
    else if (idx < 16384 + 65536) Wv_b[idx - 16384] = f2b(Wv[idx - 16384]);
  }
}

// ---------------------------------------------------------------------------
// Kernel 2: FUSED transpose + projections. Per block (b, n0 of 64 rows):
// build bf16 [64n][256c] LDS tile from f1 (inline transpose, prep_transpose
// pattern) -> Q MFMA phase; rebuild from f2 -> K + V MFMA phases. The MFMA /
// bias / store code is the round-5-verified proj body, reading fragments
// from LDS instead of global. Kills the 48MB f1T/f2T HBM round-trip.
// ---------------------------------------------------------------------------
__global__ __launch_bounds__(256) void proj_fused(
    const float* __restrict__ f1, const float* __restrict__ f2,
    const short* __restrict__ Wq_b, const float* __restrict__ bq,
    const short* __restrict__ Wk_b, const float* __restrict__ bk,
    const short* __restrict__ Wv_b, const float* __restrict__ bv,
    short* __restrict__ q_ws, short* __restrict__ k_ws,
    short* __restrict__ v_ws) {
  __shared__ float ftile[64][65];   // f32 staging (16.6 KB)
  __shared__ short T[64][264];      // bf16 [n][c] tile, +8 pad (33.8 KB)
  const int bx = blockIdx.x;
  const int b = bx >> 6;
  const int n0 = (bx & 63) * 64;
  const int tid = threadIdx.x;
  const int w = tid >> 6;
  const int lane = tid & 63;
  const int l16 = lane & 15;
  const int g = lane >> 4;
  const int lane64 = tid & 63;
  const int row4 = tid >> 6;

  auto build = [&](const float* __restrict__ src) {
#pragma unroll
    for (int cc = 0; cc < 4; ++cc) {
      __syncthreads();  // prior readers of ftile/T done
#pragma unroll
      for (int i = 0; i < 16; ++i) {
        const int cl = row4 + i * 4;
        ftile[cl][lane64] =
            src[(size_t)(b * Cc + cc * 64 + cl) * Nn + n0 + lane64];
      }
      __syncthreads();
#pragma unroll
      for (int i = 0; i < 16; ++i) {
        const int nl = row4 + i * 4;
        T[nl][cc * 64 + lane64] = f2b(ftile[lane64][nl]);
      }
    }
    __syncthreads();  // T complete
  };

  auto qk_phase = [&](const short* __restrict__ Wm,
                      const float* __restrict__ bias_p,
                      short* __restrict__ outp) {
    f32x4 accq[2] = {(f32x4){0.f, 0.f, 0.f, 0.f}, (f32x4){0.f, 0.f, 0.f, 0.f}};
#pragma unroll
    for (int kc = 0; kc < 8; ++kc) {
      const bf16x8 a = *(const bf16x8*)&T[w * 16 + l16][kc * 32 + g * 8];
#pragma unroll
      for (int ob = 0; ob < 2; ++ob) {
        const bf16x8 bb = *(const bf16x8*)&Wm[(ob * 16 + l16) * Cc + kc * 32 + g * 8];
        accq[ob] = __builtin_amdgcn_mfma_f32_16x16x32_bf16(a, bb, accq[ob], 0, 0, 0);
      }
    }
#pragma unroll
    for (int ob = 0; ob < 2; ++ob) {
      const float bias = bias_p[ob * 16 + l16];
#pragma unroll
      for (int r = 0; r < 4; ++r) {
        const int n = n0 + w * 16 + g * 4 + r;
        outp[(size_t)(b * Nn + n) * Dq + ob * 16 + l16] = f2b(accq[ob][r] + bias);
      }
    }
  };

  // ---- phase 1: T <- f1, compute Q
  build(f1);
  qk_phase(Wq_b, bq, q_ws);
  __syncthreads();  // Q reads done before T overwrite

  // ---- phase 2: T <- f2, compute K and V
  build(f2);
  qk_phase(Wk_b, bk, k_ws);
  {
    f32x4 acc[4][4];
#pragma unroll
    for (int ci = 0; ci < 4; ++ci)
#pragma unroll
      for (int nb = 0; nb < 4; ++nb) acc[ci][nb] = (f32x4){0.f, 0.f, 0.f, 0.f};
#pragma unroll
    for (int kc = 0; kc < 8; ++kc) {
      bf16x8 bfr[4];
#pragma unroll
      for (int nb = 0; nb < 4; ++nb)
        bfr[nb] = *(const bf16x8*)&T[nb * 16 + l16][kc * 32 + g * 8];
#pragma unroll
      for (int ci = 0; ci < 4; ++ci) {
        const bf16x8 afr = *(const bf16x8*)&Wv_b[((w * 4 + ci) * 16 + l16) * Cc + kc * 32 + g * 8];
#pragma unroll
        for (int nb = 0; nb < 4; ++nb)
          acc[ci][nb] = __builtin_amdgcn_mfma_f32_16x16x32_bf16(afr, bfr[nb], acc[ci][nb], 0, 0, 0);
      }
    }
#pragma unroll
    for (int ci = 0; ci < 4; ++ci) {
#pragma unroll
      for (int r = 0; r < 4; ++r) {
        const int c = (w * 4 + ci) * 16 + g * 4 + r;
        const float bias = bv[c];
#pragma unroll
        for (int nb = 0; nb < 4; ++nb) {
          const int n = n0 + nb * 16 + l16;
          v_ws[(size_t)(b * Cc + c) * Nn + n] = f2b(acc[ci][nb][r] + bias);
        }
      }
    }
  }
}

// ---------------------------------------------------------------------------
// Kernel 3: flash attention, 32x32 MFMA, in-register P with rho-permuted K
// rows (round-7 verified layout, NT=64 staging / 128B V rows / 8-slot XOR),
// SKEWED at 32-key chunk granularity: softmax(chunk i+1) [VALU] overlaps
// PV(chunk i) [MFMA+LDS]. Register ping-pong puA/puB (static indices).
// 1 barrier per 64-key tile. Defer-max THR=8 per chunk. setprio around PV.
// Epilogue: per-wave LDS transpose -> Opart [ks][b][c][m] + (m,l).
// ---------------------------------------------------------------------------
constexpr int NT = 64;
constexpr int VBUF = 256 * NT * 2;   // 32768 B per buffer ([c][8 granules])
constexpr int SBYTES = 2 * VBUF;     // 65536

template <int KS>
__global__ __launch_bounds__(256, 2) void attn_kernel(
    const short* __restrict__ q_ws, const short* __restrict__ k_ws,
    const short* __restrict__ v_ws, short* __restrict__ Opart,
    float* __restrict__ mlm, short* __restrict__ mll) {
  constexpr int KSPAN = Nn / KS;
  constexpr int NTILES = KSPAN / NT;
  __shared__ __align__(16) char smem[SBYTES];
  const int bx = blockIdx.x;
  const int swz = (bx & 7) * (16 * KS) + (bx >> 3);  // XCD-bijective
  const int ks = swz >> 7;
  const int rem = swz & 127;
  const int b = rem >> 5;
  const int m0 = (rem & 31) * 128;
  const int n0 = ks * KSPAN;
  const int tid = threadIdx.x;
  const int w = tid >> 6;
  const int lane = tid & 63;
  const int l31 = lane & 31;
  const int h = lane >> 5;

  // Q B-frags (persist): col m = m0 + w*32 + l31, k = s*16 + 8h + j
  const short* qbase = q_ws + (size_t)(b * Nn + m0 + w * 32 + l31) * Dq + h * 8;
  const bf16x8 qf0 = *(const bf16x8*)(qbase);
  const bf16x8 qf1 = *(const bf16x8*)(qbase + 16);

  // K A-frags at permuted row rho(l31) = swap bits 2<->3 (round-7 verified)
  const int kswap = (l31 & 0x13) | ((l31 & 4) << 1) | ((l31 & 8) >> 1);
  const short* kptr = k_ws + (size_t)(b * Nn + n0 + kswap) * Dq + h * 8;

  // V stage: granule (c = j*32 + tid>>3, slot = tid&7); source pre-swizzled
  // (slot ^= c&7) so the linear LDS-DMA lands the swizzled image. (r7)
  const int cth = tid >> 3;
  const int c7 = cth & 7;
  const int koff = 8 * ((tid & 7) ^ c7);
  const short* vsrc[8];
#pragma unroll
  for (int j = 0; j < 8; ++j)
    vsrc[j] = v_ws + (size_t)(b * Cc + j * 32 + cth) * Nn + n0 + koff;

  f32x16 acc[8] = {};  // O[m-pattern reg][c = cb*32 + l31]
  float mrun = -INFINITY, lrun = 0.f;

  // ---- prologue: stage tile0; K chunk0; barrier; softmax(0); stage tile1
#pragma unroll
  for (int j = 0; j < 8; ++j) {
    char* ldst = &smem[(j * 256 + tid) * 16];
    __builtin_amdgcn_global_load_lds(GLB1(vsrc[j]), LDS3(ldst), 16, 0, 0);
    vsrc[j] += NT;
  }
  bf16x8 kfa = *(const bf16x8*)(kptr);
  bf16x8 kfb = *(const bf16x8*)(kptr + 16);
  kptr += 32 * Dq;
  asm volatile("s_waitcnt vmcnt(0)" ::: "memory");
  __syncthreads();

  const f32x16 Z = {};
  unsigned puA[8], puB[8];
  // chunk 0 -> puA
  {
    f32x16 sa = __builtin_amdgcn_mfma_f32_32x32x16_bf16(kfa, qf0, Z, 0, 0, 0);
    sa = __builtin_amdgcn_mfma_f32_32x32x16_bf16(kfb, qf1, sa, 0, 0, 0);
    kfa = *(const bf16x8*)(kptr);          // K chunk 1
    kfb = *(const bf16x8*)(kptr + 16);
    kptr += 32 * Dq;
    float t8[8], t4[4];
#pragma unroll
    for (int i = 0; i < 8; ++i) t8[i] = fmaxf(sa[i], sa[i + 8]);
#pragma unroll
    for (int i = 0; i < 4; ++i) t4[i] = fmaxf(t8[i], t8[i + 4]);
    float tmax = fmaxf(fmaxf(t4[0], t4[2]), fmaxf(t4[1], t4[3]));
    tmax = fmaxf(tmax, __shfl_xor(tmax, 32));
    mrun = tmax;
    const float nml = -mrun * L2E;
    float p[16];
#pragma unroll
    for (int r = 0; r < 16; ++r) p[r] = exp2f(fmaf(sa[r], L2E, nml));
#pragma unroll
    for (int q = 0; q < 8; ++q)
      puA[q] = __builtin_amdgcn_perm(fb(p[2 * q + 1]), fb(p[2 * q]), 0x07060302u);
    float s8[8], s4[4];
#pragma unroll
    for (int i = 0; i < 8; ++i) s8[i] = p[i] + p[i + 8];
#pragma unroll
    for (int i = 0; i < 4; ++i) s4[i] = s8[i] + s8[i + 4];
    float psum = (s4[0] + s4[2]) + (s4[1] + s4[3]);
    psum += __shfl_xor(psum, 32);
    lrun = psum;
  }
  // stage tile1 -> buf1
#pragma unroll
  for (int j = 0; j < 8; ++j) {
    char* ldst = &smem[VBUF + (j * 256 + tid) * 16];
    __builtin_amdgcn_global_load_lds(GLB1(vsrc[j]), LDS3(ldst), 16, 0, 0);
    vsrc[j] += NT;
  }

  // ---- main loop: tile t holds chunks (2t, 2t+1) in buf (t&1)
  for (int t = 0; t < NTILES; ++t) {
    const int sb = (t & 1) * VBUF;
    const bool have2 = (t + 1 < NTILES);

    // QK chunk 2t+1 (kf pre-loaded)
    f32x16 sa = __builtin_amdgcn_mfma_f32_32x32x16_bf16(kfa, qf0, Z, 0, 0, 0);
    sa = __builtin_amdgcn_mfma_f32_32x32x16_bf16(kfb, qf1, sa, 0, 0, 0);
    if (have2) {
      kfa = *(const bf16x8*)(kptr);        // K chunk 2t+2
      kfb = *(const bf16x8*)(kptr + 16);
      kptr += 32 * Dq;
    }
    float t8[8], t4[4];
#pragma unroll
    for (int i = 0; i < 8; ++i) t8[i] = fmaxf(sa[i], sa[i + 8]);
#pragma unroll
    for (int i = 0; i < 4; ++i) t4[i] = fmaxf(t8[i], t8[i + 4]);
    float tmax = fmaxf(fmaxf(t4[0], t4[2]), fmaxf(t4[1], t4[3]));
    tmax = fmaxf(tmax, __shfl_xor(tmax, 32));
    const bool resc = __any(tmax > mrun + 8.f);

    // ---- PV chunk A (keys 64t .. 64t+31), overlaps the VALU above/below
    __builtin_amdgcn_s_setprio(1);
#pragma unroll
    for (int fl = 0; fl < 2; ++fl) {
      const uint4v au = {puA[4 * fl], puA[4 * fl + 1], puA[4 * fl + 2], puA[4 * fl + 3]};
      const bf16x8 A = __builtin_bit_cast(bf16x8, au);
      const int sg = 2 * fl + h;           // ch=0
      const char* vbase = &smem[sb + l31 * 128 + ((sg ^ (l31 & 7)) << 4)];
#pragma unroll
      for (int cb = 0; cb < 8; ++cb) {
        const bf16x8 vB = *(const bf16x8*)(vbase + cb * 4096);
        acc[cb] = __builtin_amdgcn_mfma_f32_32x32x16_bf16(A, vB, acc[cb], 0, 0, 0);
      }
    }
    __builtin_amdgcn_s_setprio(0);

    if (resc) {  // deferred rescale (after PV A, before PV B)
      const float mnew = fmaxf(mrun, tmax);
      const float scl = exp2f((mrun - mnew) * L2E);
      float sv[16];
#pragma unroll
      for (int r = 0; r < 16; ++r)
        sv[r] = __shfl(scl, (r & 3) + 8 * (r >> 2) + 4 * h);
#pragma unroll
      for (int cb = 0; cb < 8; ++cb)
#pragma unroll
        for (int r = 0; r < 16; ++r) acc[cb][r] *= sv[r];
      lrun *= scl;
      mrun = mnew;
    }
    {  // exp chunk 2t+1 -> puB
      const float nml = -mrun * L2E;
      float p[16];
#pragma unroll
      for (int r = 0; r < 16; ++r) p[r] = exp2f(fmaf(sa[r], L2E, nml));
#pragma unroll
      for (int q = 0; q < 8; ++q)
        puB[q] = __builtin_amdgcn_perm(fb(p[2 * q + 1]), fb(p[2 * q]), 0x07060302u);
      float s8[8], s4[4];
#pragma unroll
      for (int i = 0; i < 8; ++i) s8[i] = p[i] + p[i + 8];
#pragma unroll
      for (int i = 0; i < 4; ++i) s4[i] = s8[i] + s8[i + 4];
      float psum = (s4[0] + s4[2]) + (s4[1] + s4[3]);
      psum += __shfl_xor(psum, 32);
      lrun += psum;
    }

    // QK chunk 2t+2 (first chunk of next tile) — overlaps PV B below
    f32x16 sa2 = Z;
    float tmax2 = 0.f;
    bool resc2 = false;
    if (have2) {
      sa2 = __builtin_amdgcn_mfma_f32_32x32x16_bf16(kfa, qf0, Z, 0, 0, 0);
      sa2 = __builtin_amdgcn_mfma_f32_32x32x16_bf16(kfb, qf1, sa2, 0, 0, 0);
      kfa = *(const bf16x8*)(kptr);        // K chunk 2t+3
      kfb = *(const bf16x8*)(kptr + 16);
      kptr += 32 * Dq;
      float u8[8], u4[4];
#pragma unroll
      for (int i = 0; i < 8; ++i) u8[i] = fmaxf(sa2[i], sa2[i + 8]);
#pragma unroll
      for (int i = 0; i < 4; ++i) u4[i] = fmaxf(u8[i], u8[i + 4]);
      tmax2 = fmaxf(fmaxf(u4[0], u4[2]), fmaxf(u4[1], u4[3]));
      tmax2 = fmaxf(tmax2, __shfl_xor(tmax2, 32));
      resc2 = __any(tmax2 > mrun + 8.f);
    }

    // ---- PV chunk B (keys 64t+32 .. 64t+63)
    __builtin_amdgcn_s_setprio(1);
#pragma unroll
    for (int fl = 0; fl < 2; ++fl) {
      const uint4v au = {puB[4 * fl], puB[4 * fl + 1], puB[4 * fl + 2], puB[4 * fl + 3]};
      const bf16x8 A = __builtin_bit_cast(bf16x8, au);
      const int sg = 4 + 2 * fl + h;       // ch=1
      const char* vbase = &smem[sb + l31 * 128 + ((sg ^ (l31 & 7)) << 4)];
#pragma unroll
      for (int cb = 0; cb < 8; ++cb) {
        const bf16x8 vB = *(const bf16x8*)(vbase + cb * 4096);
        acc[cb] = __builtin_amdgcn_mfma_f32_32x32x16_bf16(A, vB, acc[cb], 0, 0, 0);
      }
    }
    __builtin_amdgcn_s_setprio(0);

    if (have2) {
      if (resc2) {
        const float mnew = fmaxf(mrun, tmax2);
        const float scl = exp2f((mrun - mnew) * L2E);
        float sv[16];
#pragma unroll
        for (int r = 0; r < 16; ++r)
          sv[r] = __shfl(scl, (r & 3) + 8 * (r >> 2) + 4 * h);
#pragma unroll
        for (int cb = 0; cb < 8; ++cb)
#pragma unroll
          for (int r = 0; r < 16; ++r) acc[cb][r] *= sv[r];
        lrun *= scl;
        mrun = mnew;
      }
      {  // exp chunk 2t+2 -> puA
        const float nml = -mrun * L2E;
        float p[16];
#pragma unroll
        for (int r = 0; r < 16; ++r) p[r] = exp2f(fmaf(sa2[r], L2E, nml));
#pragma unroll
        for (int q = 0; q < 8; ++q)
          puA[q] = __builtin_amdgcn_perm(fb(p[2 * q + 1]), fb(p[2 * q]), 0x07060302u);
        float s8[8], s4[4];
#pragma unroll
        for (int i = 0; i < 8; ++i) s8[i] = p[i] + p[i + 8];
#pragma unroll
        for (int i = 0; i < 4; ++i) s4[i] = s8[i] + s8[i + 4];
        float psum = (s4[0] + s4[2]) + (s4[1] + s4[3]);
        psum += __shfl_xor(psum, 32);
        lrun += psum;
      }
      asm volatile("s_waitcnt vmcnt(0)" ::: "memory");  // tile t+1 staged
      __syncthreads();
      if (t + 2 < NTILES) {
#pragma unroll
        for (int j = 0; j < 8; ++j) {       // stage tile t+2 -> freed buffer
          char* ldst = &smem[sb + (j * 256 + tid) * 16];
          __builtin_amdgcn_global_load_lds(GLB1(vsrc[j]), LDS3(ldst), 16, 0, 0);
          vsrc[j] += NT;
        }
      }
    }
  }

  // ---- epilogue: (m,l) + per-wave LDS transpose -> Opart [ks][b][c][m]
  __syncthreads();  // all PV done; smem reusable as transpose strips
  if (h == 0) {
    const int m = m0 + w * 32 + l31;
    mlm[(size_t)(ks * Bc + b) * Nn + m] = mrun;
    mll[(size_t)(ks * Bc + b) * Nn + m] = f2b(lrun);
  }
  char* strip = smem + w * 10240;  // [128 c][80 B] per wave, private
#pragma unroll
  for (int ph = 0; ph < 2; ++ph) {
#pragma unroll
    for (int cb2 = 0; cb2 < 4; ++cb2) {
      const int cb = ph * 4 + cb2;
      const int cs = cb2 * 32 + l31;
#pragma unroll
      for (int q = 0; q < 8; ++q) {   // m-pairs: regs (2q, 2q+1)
        const int mloc = ((2 * q) & 3) + 8 * (q >> 1) + 4 * h;
        const unsigned pv = __builtin_amdgcn_perm(
            fb(acc[cb][2 * q + 1]), fb(acc[cb][2 * q]), 0x07060302u);
        *(unsigned*)(strip + cs * 80 + mloc * 2) = pv;
      }
    }
    asm volatile("s_waitcnt lgkmcnt(0)" ::: "memory");
#pragma unroll
    for (int i = 0; i < 8; ++i) {
      const int gi = i * 64 + lane;
      const int cs = gi >> 2, gq = gi & 3;
      const uint4v vv = *(const uint4v*)(strip + cs * 80 + gq * 16);
      const int cg = ph * 128 + cs;
      const size_t off =
          ((size_t)(ks * Bc + b) * Cc + cg) * Nn + m0 + w * 32 + gq * 8;
      *(uint4v*)&Opart[off] = vv;
    }
    asm volatile("s_waitcnt lgkmcnt(0)" ::: "memory");
  }
}

// ---------------------------------------------------------------------------
// Kernel 4: combine KS key-splits + residual (pure streaming, no transpose).
// ---------------------------------------------------------------------------
template <int KS>
__global__ __launch_bounds__(256) void combine_kernel(
    const short* __restrict__ Opart, const float* __restrict__ mlm,
    const short* __restrict__ mll, const float* __restrict__ feat1,
    const float* __restrict__ gamma_p, float* __restrict__ out) {
  __shared__ float aLDS[KS][64];
  const int bx = blockIdx.x;       // b*64 + mrange
  const int b = bx >> 6;
  const int m0 = (bx & 63) * 64;
  const int tid = threadIdx.x;
  if (tid < 64) {
    const int m = m0 + tid;
    float mm[KS], ll[KS], ms = -INFINITY;
#pragma unroll
    for (int ks = 0; ks < KS; ++ks) {
      mm[ks] = mlm[(size_t)(ks * Bc + b) * Nn + m];
      ll[ks] = b2f(mll[(size_t)(ks * Bc + b) * Nn + m]);
      ms = fmaxf(ms, mm[ks]);
    }
    float es[KS], lsum = 0.f;
#pragma unroll
    for (int ks = 0; ks < KS; ++ks) {
      es[ks] = exp2f((mm[ks] - ms) * L2E);
      lsum += ll[ks] * es[ks];
    }
    const float inv = 1.f / lsum;
#pragma unroll
    for (int ks = 0; ks < KS; ++ks) aLDS[ks][tid] = es[ks] * inv;
  }
  __syncthreads();
  const int mg = tid & 7;          // m-granule (8 m's)
  const int cb = tid >> 3;         // 0..31
  float aks[KS][8];
#pragma unroll
  for (int ks = 0; ks < KS; ++ks)
#pragma unroll
    for (int j = 0; j < 8; ++j) aks[ks][j] = aLDS[ks][mg * 8 + j];
  const float gam = gamma_p[0];
#pragma unroll 2
  for (int i = 0; i < 8; ++i) {
    const int c = cb + i * 32;
    float v[8] = {0.f, 0.f, 0.f, 0.f, 0.f, 0.f, 0.f, 0.f};
#pragma unroll
    for (int ks = 0; ks < KS; ++ks) {
      const bf16x8 ov = *(const bf16x8*)
          &Opart[((size_t)(ks * Bc + b) * Cc + c) * Nn + m0 + mg * 8];
#pragma unroll
      for (int j = 0; j < 8; ++j) v[j] += b2f(ov[j]) * aks[ks][j];
    }
    const size_t base = ((size_t)(b * Cc + c)) * Nn + m0 + mg * 8;
    const f32x4 fa = *(const f32x4*)&feat1[base];
    const f32x4 fbv = *(const f32x4*)&feat1[base + 4];
    f32x4 o0, o1;
#pragma unroll
    for (int j = 0; j < 4; ++j) {
      o0[j] = gam * v[j] + fa[j];
      o1[j] = gam * v[4 + j] + fbv[j];
    }
    *(f32x4*)&out[base] = o0;
    *(f32x4*)&out[base + 4] = o1;
  }
}

// ---------------------------------------------------------------------------
// Launch
// ---------------------------------------------------------------------------
extern "C" void kernel_launch(void* const* d_in, const int* in_sizes, int n_in,
                              void* d_out, int out_size, void* d_ws,
                              size_t ws_size, hipStream_t stream) {
  const float* feat1 = (const float*)d_in[0];
  const float* feat2 = (const float*)d_in[1];
  const float* Wq = (const float*)d_in[2];
  const float* bq = (const float*)d_in[3];
  const float* Wk = (const float*)d_in[4];
  const float* bk = (const float*)d_in[5];
  const float* Wv = (const float*)d_in[6];
  const float* bv = (const float*)d_in[7];
  const float* gamma = (const float*)d_in[8];
  float* out = (float*)d_out;
  char* ws = (char*)d_ws;

  const size_t need4 = 44433408;  // proven ws >= 44466176 (round-5 KS=2 ran)
  if (ws_size >= need4) {
    // KS=4 layout. Weights overlay Opart (consumed before attn writes it).
    short* Opart = (short*)(ws + 0);          // 32 MiB [4][4][256][4096] bf16
    short* Wq_b = (short*)(ws + 16777216);    // 16 KiB (overlay)
    short* Wk_b = (short*)(ws + 16793600);
    short* Wv_b = (short*)(ws + 16809984);    // 128 KiB (overlay)
    short* q_ws = (short*)(ws + 33554432);    // 1 MiB
    short* k_ws = (short*)(ws + 34603008);    // 1 MiB
    short* v_ws = (short*)(ws + 35651584);    // 8 MiB
    float* mlm  = (float*)(ws + 44040192);    // 256 KiB f32
    short* mll  = (short*)(ws + 44302336);    // 128 KiB bf16

    prep_weights<<<80, 256, 0, stream>>>(Wq, Wk, Wv, Wq_b, Wk_b, Wv_b);
    proj_fused<<<256, 256, 0, stream>>>(feat1, feat2, Wq_b, bq, Wk_b, bk,
                                        Wv_b, bv, q_ws, k_ws, v_ws);
    attn_kernel<4><<<512, 256, 0, stream>>>(q_ws, k_ws, v_ws, Opart, mlm, mll);
    combine_kernel<4><<<256, 256, 0, stream>>>(Opart, mlm, mll, feat1, gamma,
                                               out);
  } else {
    // KS=2 fallback (~27.7 MiB).
    short* Opart = (short*)(ws + 0);          // 16 MiB
    short* Wq_b = (short*)(ws + 16777216);
    short* Wk_b = (short*)(ws + 16793600);
    short* Wv_b = (short*)(ws + 16809984);
    short* q_ws = (short*)(ws + 16941056);
    short* k_ws = (short*)(ws + 17989632);
    short* v_ws = (short*)(ws + 19038208);
    float* mlm  = (float*)(ws + 27426816);
    short* mll  = (short*)(ws + 27557888);

    prep_weights<<<80, 256, 0, stream>>>(Wq, Wk, Wv, Wq_b, Wk_b, Wv_b);
    proj_fused<<<256, 256, 0, stream>>>(feat1, feat2, Wq_b, bq, Wk_b, bk,
                                        Wv_b, bv, q_ws, k_ws, v_ws);
    attn_kernel<2><<<256, 256, 0, stream>>>(q_ws, k_ws, v_ws, Opart, mlm, mll);
    combine_kernel<2><<<256, 256, 0, stream>>>(Opart, mlm, mll, feat1, gamma,
                                               out);
  }
}

// Round 10
// 96.363 us; speedup vs baseline: 1.1651x; 1.0251x over previous
//
#include <hip/hip_runtime.h>
#include <hip/hip_bf16.h>
#include <stdint.h>

typedef __attribute__((ext_vector_type(8))) short bf16x8;
typedef __attribute__((ext_vector_type(4))) short short4v;
typedef __attribute__((ext_vector_type(4))) float f32x4;
typedef __attribute__((ext_vector_type(16))) float f32x16;
typedef __attribute__((ext_vector_type(4))) unsigned uint4v;

#define LDS3(p) ((__attribute__((address_space(3))) void*)(p))
#define GLB1(p) ((const __attribute__((address_space(1))) void*)(p))

constexpr int Bc = 4;
constexpr int Cc = 256;   // channels (= d_v)
constexpr int Nn = 4096;  // H*W
constexpr int Dq = 32;    // C/8 (= d_qk)
constexpr float L2E = 1.4426950408889634f;

__device__ __forceinline__ short f2b(float x) {
  union { float f; uint32_t u; } v; v.f = x;
  uint32_t r = (v.u + 0x7fffu + ((v.u >> 16) & 1u)) >> 16;  // RNE
  return (short)(r & 0xffffu);
}
__device__ __forceinline__ float b2f(short s) {
  union { uint32_t u; float f; } v; v.u = ((uint32_t)(uint16_t)s) << 16;
  return v.f;
}
__device__ __forceinline__ unsigned fb(float x) {
  union { float f; unsigned u; } v; v.f = x; return v.u;
}

// ---------------------------------------------------------------------------
// Kernel 1: convert weights f32 -> bf16 (layouts preserved: [out][in])
// ---------------------------------------------------------------------------
__global__ __launch_bounds__(256) void prep_weights(
    const float* __restrict__ Wq, const float* __restrict__ Wk,
    const float* __restrict__ Wv, short* __restrict__ Wq_b,
    short* __restrict__ Wk_b, short* __restrict__ Wv_b) {
  const int base = (blockIdx.x * 256 + threadIdx.x) * 4;
#pragma unroll
  for (int j = 0; j < 4; ++j) {
    const int idx = base + j;
    if (idx < 8192) Wq_b[idx] = f2b(Wq[idx]);
    else if (idx < 16384) Wk_b[idx - 8192] = f2b(Wk[idx - 8192]);
    else if (idx < 16384 + 65536) Wv_b[idx - 16384] = f2b(Wv[idx - 16384]);
  }
}

// ---------------------------------------------------------------------------
// Kernel 2: FUSED transpose + projections (round-9 verified).
// ---------------------------------------------------------------------------
__global__ __launch_bounds__(256) void proj_fused(
    const float* __restrict__ f1, const float* __restrict__ f2,
    const short* __restrict__ Wq_b, const float* __restrict__ bq,
    const short* __restrict__ Wk_b, const float* __restrict__ bk,
    const short* __restrict__ Wv_b, const float* __restrict__ bv,
    short* __restrict__ q_ws, short* __restrict__ k_ws,
    short* __restrict__ v_ws) {
  __shared__ float ftile[64][65];   // f32 staging (16.6 KB)
  __shared__ short T[64][264];      // bf16 [n][c] tile, +8 pad (33.8 KB)
  const int bx = blockIdx.x;
  const int b = bx >> 6;
  const int n0 = (bx & 63) * 64;
  const int tid = threadIdx.x;
  const int w = tid >> 6;
  const int lane = tid & 63;
  const int l16 = lane & 15;
  const int g = lane >> 4;
  const int lane64 = tid & 63;
  const int row4 = tid >> 6;

  auto build = [&](const float* __restrict__ src) {
#pragma unroll
    for (int cc = 0; cc < 4; ++cc) {
      __syncthreads();  // prior readers of ftile/T done
#pragma unroll
      for (int i = 0; i < 16; ++i) {
        const int cl = row4 + i * 4;
        ftile[cl][lane64] =
            src[(size_t)(b * Cc + cc * 64 + cl) * Nn + n0 + lane64];
      }
      __syncthreads();
#pragma unroll
      for (int i = 0; i < 16; ++i) {
        const int nl = row4 + i * 4;
        T[nl][cc * 64 + lane64] = f2b(ftile[lane64][nl]);
      }
    }
    __syncthreads();  // T complete
  };

  auto qk_phase = [&](const short* __restrict__ Wm,
                      const float* __restrict__ bias_p,
                      short* __restrict__ outp) {
    f32x4 accq[2] = {(f32x4){0.f, 0.f, 0.f, 0.f}, (f32x4){0.f, 0.f, 0.f, 0.f}};
#pragma unroll
    for (int kc = 0; kc < 8; ++kc) {
      const bf16x8 a = *(const bf16x8*)&T[w * 16 + l16][kc * 32 + g * 8];
#pragma unroll
      for (int ob = 0; ob < 2; ++ob) {
        const bf16x8 bb = *(const bf16x8*)&Wm[(ob * 16 + l16) * Cc + kc * 32 + g * 8];
        accq[ob] = __builtin_amdgcn_mfma_f32_16x16x32_bf16(a, bb, accq[ob], 0, 0, 0);
      }
    }
#pragma unroll
    for (int ob = 0; ob < 2; ++ob) {
      const float bias = bias_p[ob * 16 + l16];
#pragma unroll
      for (int r = 0; r < 4; ++r) {
        const int n = n0 + w * 16 + g * 4 + r;
        outp[(size_t)(b * Nn + n) * Dq + ob * 16 + l16] = f2b(accq[ob][r] + bias);
      }
    }
  };

  // ---- phase 1: T <- f1, compute Q
  build(f1);
  qk_phase(Wq_b, bq, q_ws);
  __syncthreads();  // Q reads done before T overwrite

  // ---- phase 2: T <- f2, compute K and V
  build(f2);
  qk_phase(Wk_b, bk, k_ws);
  {
    f32x4 acc[4][4];
#pragma unroll
    for (int ci = 0; ci < 4; ++ci)
#pragma unroll
      for (int nb = 0; nb < 4; ++nb) acc[ci][nb] = (f32x4){0.f, 0.f, 0.f, 0.f};
#pragma unroll
    for (int kc = 0; kc < 8; ++kc) {
      bf16x8 bfr[4];
#pragma unroll
      for (int nb = 0; nb < 4; ++nb)
        bfr[nb] = *(const bf16x8*)&T[nb * 16 + l16][kc * 32 + g * 8];
#pragma unroll
      for (int ci = 0; ci < 4; ++ci) {
        const bf16x8 afr = *(const bf16x8*)&Wv_b[((w * 4 + ci) * 16 + l16) * Cc + kc * 32 + g * 8];
#pragma unroll
        for (int nb = 0; nb < 4; ++nb)
          acc[ci][nb] = __builtin_amdgcn_mfma_f32_16x16x32_bf16(afr, bfr[nb], acc[ci][nb], 0, 0, 0);
      }
    }
#pragma unroll
    for (int ci = 0; ci < 4; ++ci) {
#pragma unroll
      for (int r = 0; r < 4; ++r) {
        const int c = (w * 4 + ci) * 16 + g * 4 + r;
        const float bias = bv[c];
#pragma unroll
        for (int nb = 0; nb < 4; ++nb) {
          const int n = n0 + nb * 16 + l16;
          v_ws[(size_t)(b * Cc + c) * Nn + n] = f2b(acc[ci][nb][r] + bias);
        }
      }
    }
  }
}

// ---------------------------------------------------------------------------
// Kernel 3: flash attention — ROUND-7 VERIFIED STRUCTURE (NT=64, single
// 64-key softmax per tile, no skew, 1 barrier/tile), 32x32 MFMA,
// in-register P with rho-permuted K rows. Micro-polish only:
// setprio(1) around PV cluster (T5), max3-shaped reduction trees (T17).
// ---------------------------------------------------------------------------
constexpr int NT = 64;
constexpr int VBUF = 256 * NT * 2;   // 32768 B per buffer ([c][8 granules])
constexpr int SBYTES = 2 * VBUF;     // 65536

template <int KS>
__global__ __launch_bounds__(256, 2) void attn_kernel(
    const short* __restrict__ q_ws, const short* __restrict__ k_ws,
    const short* __restrict__ v_ws, short* __restrict__ Opart,
    float* __restrict__ mlm, short* __restrict__ mll) {
  constexpr int KSPAN = Nn / KS;
  constexpr int NTILES = KSPAN / NT;
  __shared__ __align__(16) char smem[SBYTES];
  const int bx = blockIdx.x;
  const int swz = (bx & 7) * (16 * KS) + (bx >> 3);  // XCD-bijective
  const int ks = swz >> 7;
  const int rem = swz & 127;
  const int b = rem >> 5;
  const int m0 = (rem & 31) * 128;
  const int n0 = ks * KSPAN;
  const int tid = threadIdx.x;
  const int w = tid >> 6;
  const int lane = tid & 63;
  const int l31 = lane & 31;
  const int h = lane >> 5;

  // Q B-frags (persist): col m = m0 + w*32 + l31, k = s*16 + 8h + j
  const short* qbase = q_ws + (size_t)(b * Nn + m0 + w * 32 + l31) * Dq + h * 8;
  const bf16x8 qf0 = *(const bf16x8*)(qbase);
  const bf16x8 qf1 = *(const bf16x8*)(qbase + 16);

  // K A-frags at permuted row rho(l31) = swap bits 2<->3 (round-7 verified)
  const int kswap = (l31 & 0x13) | ((l31 & 4) << 1) | ((l31 & 8) >> 1);
  const short* kptr = k_ws + (size_t)(b * Nn + n0 + kswap) * Dq + h * 8;

  // V stage: granule (c = j*32 + tid>>3, slot = tid&7); source pre-swizzled
  // (slot ^= c&7) so the linear LDS-DMA lands the swizzled image.
  const int cth = tid >> 3;
  const int c7 = cth & 7;
  const int koff = 8 * ((tid & 7) ^ c7);
  const short* vsrc[8];
#pragma unroll
  for (int j = 0; j < 8; ++j)
    vsrc[j] = v_ws + (size_t)(b * Cc + j * 32 + cth) * Nn + n0 + koff;

  f32x16 acc[8] = {};  // O[m-pattern reg][c = cb*32 + l31]
  float mrun = -INFINITY, lrun = 0.f;

  // prologue: stage tile 0, prefetch K(0)
#pragma unroll
  for (int j = 0; j < 8; ++j) {
    char* ldst = &smem[(j * 256 + tid) * 16];
    __builtin_amdgcn_global_load_lds(GLB1(vsrc[j]), LDS3(ldst), 16, 0, 0);
    vsrc[j] += NT;
  }
  bf16x8 kf[4];  // [nb*2 + s]
#pragma unroll
  for (int nb = 0; nb < 2; ++nb)
#pragma unroll
    for (int s = 0; s < 2; ++s)
      kf[nb * 2 + s] = *(const bf16x8*)(kptr + nb * 32 * Dq + s * 16);
  kptr += NT * Dq;

  const f32x16 Z = {};
  for (int t = 0; t < NTILES; ++t) {
    const int buf = t & 1;
    // ---- S^T = K*Q^T: lane owns row m = l31; key rows are rho-permuted
    f32x16 sa[2];
    sa[0] = __builtin_amdgcn_mfma_f32_32x32x16_bf16(kf[0], qf0, Z, 0, 0, 0);
    sa[0] = __builtin_amdgcn_mfma_f32_32x32x16_bf16(kf[1], qf1, sa[0], 0, 0, 0);
    sa[1] = __builtin_amdgcn_mfma_f32_32x32x16_bf16(kf[2], qf0, Z, 0, 0, 0);
    sa[1] = __builtin_amdgcn_mfma_f32_32x32x16_bf16(kf[3], qf1, sa[1], 0, 0, 0);

    // ---- wave-local online softmax; max3-shaped tree (clang -> v_max3)
    float m16[8];
#pragma unroll
    for (int i = 0; i < 8; ++i)
      m16[i] = fmaxf(fmaxf(sa[0][i], sa[0][i + 8]),
                     fmaxf(sa[1][i], sa[1][i + 8]));
    float m3a = fmaxf(fmaxf(m16[0], m16[1]), m16[2]);
    float m3b = fmaxf(fmaxf(m16[3], m16[4]), m16[5]);
    float m3c = fmaxf(m16[6], m16[7]);
    float tmax = fmaxf(fmaxf(m3a, m3b), m3c);
    tmax = fmaxf(tmax, __shfl_xor(tmax, 32));
    if (__any(tmax > mrun + 8.f)) {   // defer-max: rescale rarely
      const float mnew = fmaxf(mrun, tmax);
      const float scl = exp2f((mrun - mnew) * L2E);
      float sv[16];
#pragma unroll
      for (int r = 0; r < 16; ++r)
        sv[r] = __shfl(scl, (r & 3) + 8 * (r >> 2) + 4 * h);
#pragma unroll
      for (int cb = 0; cb < 8; ++cb)
#pragma unroll
        for (int r = 0; r < 16; ++r) acc[cb][r] *= sv[r];
      lrun *= scl;
      mrun = mnew;
    }
    const float nml = -mrun * L2E;
    float psum = 0.f;
    unsigned pu[16];
    {
      float p[32];
#pragma unroll
      for (int nb = 0; nb < 2; ++nb)
#pragma unroll
        for (int r = 0; r < 16; ++r)
          p[nb * 16 + r] = exp2f(fmaf(sa[nb][r], L2E, nml));
#pragma unroll
      for (int q = 0; q < 16; ++q)
        pu[q] = __builtin_amdgcn_perm(fb(p[2 * q + 1]), fb(p[2 * q]), 0x07060302u);
      float s8[8];
#pragma unroll
      for (int i = 0; i < 8; ++i)
        s8[i] = (p[i] + p[i + 8]) + (p[i + 16] + p[i + 24]);
      float s4a = (s8[0] + s8[1]) + (s8[2] + s8[3]);
      float s4b = (s8[4] + s8[5]) + (s8[6] + s8[7]);
      psum = s4a + s4b;
      psum += __shfl_xor(psum, 32);
    }
    lrun += psum;

    asm volatile("s_waitcnt vmcnt(0)" ::: "memory");  // V(t) staged
    __syncthreads();

    if (t + 1 < NTILES) {
#pragma unroll
      for (int j = 0; j < 8; ++j) {
        char* ldst = &smem[(buf ^ 1) * VBUF + (j * 256 + tid) * 16];
        __builtin_amdgcn_global_load_lds(GLB1(vsrc[j]), LDS3(ldst), 16, 0, 0);
        vsrc[j] += NT;
      }
#pragma unroll
      for (int nb = 0; nb < 2; ++nb)
#pragma unroll
        for (int s = 0; s < 2; ++s)
          kf[nb * 2 + s] = *(const bf16x8*)(kptr + nb * 32 * Dq + s * 16);
      kptr += NT * Dq;
    }

    // ---- PV: A = pu frags (direct, thanks to rho), B = V[k16][c32] LDS
    const int sb = buf * VBUF;
    __builtin_amdgcn_s_setprio(1);
#pragma unroll
    for (int f = 0; f < 4; ++f) {     // kstep: keys 16f .. 16f+15
      const uint4v au = {pu[4 * f], pu[4 * f + 1], pu[4 * f + 2], pu[4 * f + 3]};
      const bf16x8 A = __builtin_bit_cast(bf16x8, au);
      const char* vbase =
          &smem[sb + l31 * 128 + ((((f << 1) + h) ^ (l31 & 7)) << 4)];
#pragma unroll
      for (int cb = 0; cb < 8; ++cb) {
        const bf16x8 vB = *(const bf16x8*)(vbase + cb * 4096);
        acc[cb] = __builtin_amdgcn_mfma_f32_32x32x16_bf16(A, vB, acc[cb], 0, 0, 0);
      }
    }
    __builtin_amdgcn_s_setprio(0);
  }

  // ---- epilogue: (m,l) + per-wave LDS transpose -> Opart [ks][b][c][m]
  __syncthreads();  // all PV done; smem reusable as transpose strips
  if (h == 0) {
    const int m = m0 + w * 32 + l31;
    mlm[(size_t)(ks * Bc + b) * Nn + m] = mrun;
    mll[(size_t)(ks * Bc + b) * Nn + m] = f2b(lrun);
  }
  char* strip = smem + w * 10240;  // [128 c][80 B] per wave, private
#pragma unroll
  for (int ph = 0; ph < 2; ++ph) {
#pragma unroll
    for (int cb2 = 0; cb2 < 4; ++cb2) {
      const int cb = ph * 4 + cb2;
      const int cs = cb2 * 32 + l31;
#pragma unroll
      for (int q = 0; q < 8; ++q) {   // m-pairs: regs (2q, 2q+1)
        const int mloc = ((2 * q) & 3) + 8 * (q >> 1) + 4 * h;
        const unsigned pv = __builtin_amdgcn_perm(
            fb(acc[cb][2 * q + 1]), fb(acc[cb][2 * q]), 0x07060302u);
        *(unsigned*)(strip + cs * 80 + mloc * 2) = pv;
      }
    }
    asm volatile("s_waitcnt lgkmcnt(0)" ::: "memory");
#pragma unroll
    for (int i = 0; i < 8; ++i) {
      const int gi = i * 64 + lane;
      const int cs = gi >> 2, gq = gi & 3;
      const uint4v vv = *(const uint4v*)(strip + cs * 80 + gq * 16);
      const int cg = ph * 128 + cs;
      const size_t off =
          ((size_t)(ks * Bc + b) * Cc + cg) * Nn + m0 + w * 32 + gq * 8;
      *(uint4v*)&Opart[off] = vv;
    }
    asm volatile("s_waitcnt lgkmcnt(0)" ::: "memory");
  }
}

// ---------------------------------------------------------------------------
// Kernel 4: combine KS key-splits + residual (pure streaming, no transpose).
// ---------------------------------------------------------------------------
template <int KS>
__global__ __launch_bounds__(256) void combine_kernel(
    const short* __restrict__ Opart, const float* __restrict__ mlm,
    const short* __restrict__ mll, const float* __restrict__ feat1,
    const float* __restrict__ gamma_p, float* __restrict__ out) {
  __shared__ float aLDS[KS][64];
  const int bx = blockIdx.x;       // b*64 + mrange
  const int b = bx >> 6;
  const int m0 = (bx & 63) * 64;
  const int tid = threadIdx.x;
  if (tid < 64) {
    const int m = m0 + tid;
    float mm[KS], ll[KS], ms = -INFINITY;
#pragma unroll
    for (int ks = 0; ks < KS; ++ks) {
      mm[ks] = mlm[(size_t)(ks * Bc + b) * Nn + m];
      ll[ks] = b2f(mll[(size_t)(ks * Bc + b) * Nn + m]);
      ms = fmaxf(ms, mm[ks]);
    }
    float es[KS], lsum = 0.f;
#pragma unroll
    for (int ks = 0; ks < KS; ++ks) {
      es[ks] = exp2f((mm[ks] - ms) * L2E);
      lsum += ll[ks] * es[ks];
    }
    const float inv = 1.f / lsum;
#pragma unroll
    for (int ks = 0; ks < KS; ++ks) aLDS[ks][tid] = es[ks] * inv;
  }
  __syncthreads();
  const int mg = tid & 7;          // m-granule (8 m's)
  const int cb = tid >> 3;         // 0..31
  float aks[KS][8];
#pragma unroll
  for (int ks = 0; ks < KS; ++ks)
#pragma unroll
    for (int j = 0; j < 8; ++j) aks[ks][j] = aLDS[ks][mg * 8 + j];
  const float gam = gamma_p[0];
#pragma unroll 2
  for (int i = 0; i < 8; ++i) {
    const int c = cb + i * 32;
    float v[8] = {0.f, 0.f, 0.f, 0.f, 0.f, 0.f, 0.f, 0.f};
#pragma unroll
    for (int ks = 0; ks < KS; ++ks) {
      const bf16x8 ov = *(const bf16x8*)
          &Opart[((size_t)(ks * Bc + b) * Cc + c) * Nn + m0 + mg * 8];
#pragma unroll
      for (int j = 0; j < 8; ++j) v[j] += b2f(ov[j]) * aks[ks][j];
    }
    const size_t base = ((size_t)(b * Cc + c)) * Nn + m0 + mg * 8;
    const f32x4 fa = *(const f32x4*)&feat1[base];
    const f32x4 fbv = *(const f32x4*)&feat1[base + 4];
    f32x4 o0, o1;
#pragma unroll
    for (int j = 0; j < 4; ++j) {
      o0[j] = gam * v[j] + fa[j];
      o1[j] = gam * v[4 + j] + fbv[j];
    }
    *(f32x4*)&out[base] = o0;
    *(f32x4*)&out[base + 4] = o1;
  }
}

// ---------------------------------------------------------------------------
// Launch
// ---------------------------------------------------------------------------
extern "C" void kernel_launch(void* const* d_in, const int* in_sizes, int n_in,
                              void* d_out, int out_size, void* d_ws,
                              size_t ws_size, hipStream_t stream) {
  const float* feat1 = (const float*)d_in[0];
  const float* feat2 = (const float*)d_in[1];
  const float* Wq = (const float*)d_in[2];
  const float* bq = (const float*)d_in[3];
  const float* Wk = (const float*)d_in[4];
  const float* bk = (const float*)d_in[5];
  const float* Wv = (const float*)d_in[6];
  const float* bv = (const float*)d_in[7];
  const float* gamma = (const float*)d_in[8];
  float* out = (float*)d_out;
  char* ws = (char*)d_ws;

  const size_t need4 = 44433408;  // proven ws >= 44466176 (round-5 KS=2 ran)
  if (ws_size >= need4) {
    // KS=4 layout. Weights overlay Opart (consumed before attn writes it).
    short* Opart = (short*)(ws + 0);          // 32 MiB [4][4][256][4096] bf16
    short* Wq_b = (short*)(ws + 16777216);    // 16 KiB (overlay)
    short* Wk_b = (short*)(ws + 16793600);
    short* Wv_b = (short*)(ws + 16809984);    // 128 KiB (overlay)
    short* q_ws = (short*)(ws + 33554432);    // 1 MiB
    short* k_ws = (short*)(ws + 34603008);    // 1 MiB
    short* v_ws = (short*)(ws + 35651584);    // 8 MiB
    float* mlm  = (float*)(ws + 44040192);    // 256 KiB f32
    short* mll  = (short*)(ws + 44302336);    // 128 KiB bf16

    prep_weights<<<80, 256, 0, stream>>>(Wq, Wk, Wv, Wq_b, Wk_b, Wv_b);
    proj_fused<<<256, 256, 0, stream>>>(feat1, feat2, Wq_b, bq, Wk_b, bk,
                                        Wv_b, bv, q_ws, k_ws, v_ws);
    attn_kernel<4><<<512, 256, 0, stream>>>(q_ws, k_ws, v_ws, Opart, mlm, mll);
    combine_kernel<4><<<256, 256, 0, stream>>>(Opart, mlm, mll, feat1, gamma,
                                               out);
  } else {
    // KS=2 fallback (~27.7 MiB).
    short* Opart = (short*)(ws + 0);          // 16 MiB
    short* Wq_b = (short*)(ws + 16777216);
    short* Wk_b = (short*)(ws + 16793600);
    short* Wv_b = (short*)(ws + 16809984);
    short* q_ws = (short*)(ws + 16941056);
    short* k_ws = (short*)(ws + 17989632);
    short* v_ws = (short*)(ws + 19038208);
    float* mlm  = (float*)(ws + 27426816);
    short* mll  = (short*)(ws + 27557888);

    prep_weights<<<80, 256, 0, stream>>>(Wq, Wk, Wv, Wq_b, Wk_b, Wv_b);
    proj_fused<<<256, 256, 0, stream>>>(feat1, feat2, Wq_b, bq, Wk_b, bk,
                                        Wv_b, bv, q_ws, k_ws, v_ws);
    attn_kernel<2><<<256, 256, 0, stream>>>(q_ws, k_ws, v_ws, Opart, mlm, mll);
    combine_kernel<2><<<256, 256, 0, stream>>>(Opart, mlm, mll, feat1, gamma,
                                               out);
  }
}

// Round 11
// 93.934 us; speedup vs baseline: 1.1953x; 1.0259x over previous
//
#include <hip/hip_runtime.h>
#include <hip/hip_bf16.h>
#include <stdint.h>

typedef __attribute__((ext_vector_type(8))) short bf16x8;
typedef __attribute__((ext_vector_type(4))) short short4v;
typedef __attribute__((ext_vector_type(4))) float f32x4;
typedef __attribute__((ext_vector_type(16))) float f32x16;
typedef __attribute__((ext_vector_type(4))) unsigned uint4v;

#define LDS3(p) ((__attribute__((address_space(3))) void*)(p))
#define GLB1(p) ((const __attribute__((address_space(1))) void*)(p))

constexpr int Bc = 4;
constexpr int Cc = 256;   // channels (= d_v)
constexpr int Nn = 4096;  // H*W
constexpr int Dq = 32;    // C/8 (= d_qk)
constexpr float L2E = 1.4426950408889634f;

__device__ __forceinline__ short f2b(float x) {
  union { float f; uint32_t u; } v; v.f = x;
  uint32_t r = (v.u + 0x7fffu + ((v.u >> 16) & 1u)) >> 16;  // RNE
  return (short)(r & 0xffffu);
}
__device__ __forceinline__ float b2f(short s) {
  union { uint32_t u; float f; } v; v.u = ((uint32_t)(uint16_t)s) << 16;
  return v.f;
}
__device__ __forceinline__ unsigned fb(float x) {
  union { float f; unsigned u; } v; v.f = x; return v.u;
}

// ---------------------------------------------------------------------------
// Kernel 1: convert weights f32 -> bf16 (layouts preserved: [out][in])
// ---------------------------------------------------------------------------
__global__ __launch_bounds__(256) void prep_weights(
    const float* __restrict__ Wq, const float* __restrict__ Wk,
    const float* __restrict__ Wv, short* __restrict__ Wq_b,
    short* __restrict__ Wk_b, short* __restrict__ Wv_b) {
  const int base = (blockIdx.x * 256 + threadIdx.x) * 4;
#pragma unroll
  for (int j = 0; j < 4; ++j) {
    const int idx = base + j;
    if (idx < 8192) Wq_b[idx] = f2b(Wq[idx]);
    else if (idx < 16384) Wk_b[idx - 8192] = f2b(Wk[idx - 8192]);
    else if (idx < 16384 + 65536) Wv_b[idx - 16384] = f2b(Wv[idx - 16384]);
  }
}

// ---------------------------------------------------------------------------
// Kernel 2: FUSED transpose + projections (round-9 verified).
// ---------------------------------------------------------------------------
__global__ __launch_bounds__(256) void proj_fused(
    const float* __restrict__ f1, const float* __restrict__ f2,
    const short* __restrict__ Wq_b, const float* __restrict__ bq,
    const short* __restrict__ Wk_b, const float* __restrict__ bk,
    const short* __restrict__ Wv_b, const float* __restrict__ bv,
    short* __restrict__ q_ws, short* __restrict__ k_ws,
    short* __restrict__ v_ws) {
  __shared__ float ftile[64][65];   // f32 staging (16.6 KB)
  __shared__ short T[64][264];      // bf16 [n][c] tile, +8 pad (33.8 KB)
  const int bx = blockIdx.x;
  const int b = bx >> 6;
  const int n0 = (bx & 63) * 64;
  const int tid = threadIdx.x;
  const int w = tid >> 6;
  const int lane = tid & 63;
  const int l16 = lane & 15;
  const int g = lane >> 4;
  const int lane64 = tid & 63;
  const int row4 = tid >> 6;

  auto build = [&](const float* __restrict__ src) {
#pragma unroll
    for (int cc = 0; cc < 4; ++cc) {
      __syncthreads();  // prior readers of ftile/T done
#pragma unroll
      for (int i = 0; i < 16; ++i) {
        const int cl = row4 + i * 4;
        ftile[cl][lane64] =
            src[(size_t)(b * Cc + cc * 64 + cl) * Nn + n0 + lane64];
      }
      __syncthreads();
#pragma unroll
      for (int i = 0; i < 16; ++i) {
        const int nl = row4 + i * 4;
        T[nl][cc * 64 + lane64] = f2b(ftile[lane64][nl]);
      }
    }
    __syncthreads();  // T complete
  };

  auto qk_phase = [&](const short* __restrict__ Wm,
                      const float* __restrict__ bias_p,
                      short* __restrict__ outp) {
    f32x4 accq[2] = {(f32x4){0.f, 0.f, 0.f, 0.f}, (f32x4){0.f, 0.f, 0.f, 0.f}};
#pragma unroll
    for (int kc = 0; kc < 8; ++kc) {
      const bf16x8 a = *(const bf16x8*)&T[w * 16 + l16][kc * 32 + g * 8];
#pragma unroll
      for (int ob = 0; ob < 2; ++ob) {
        const bf16x8 bb = *(const bf16x8*)&Wm[(ob * 16 + l16) * Cc + kc * 32 + g * 8];
        accq[ob] = __builtin_amdgcn_mfma_f32_16x16x32_bf16(a, bb, accq[ob], 0, 0, 0);
      }
    }
#pragma unroll
    for (int ob = 0; ob < 2; ++ob) {
      const float bias = bias_p[ob * 16 + l16];
#pragma unroll
      for (int r = 0; r < 4; ++r) {
        const int n = n0 + w * 16 + g * 4 + r;
        outp[(size_t)(b * Nn + n) * Dq + ob * 16 + l16] = f2b(accq[ob][r] + bias);
      }
    }
  };

  // ---- phase 1: T <- f1, compute Q
  build(f1);
  qk_phase(Wq_b, bq, q_ws);
  __syncthreads();  // Q reads done before T overwrite

  // ---- phase 2: T <- f2, compute K and V
  build(f2);
  qk_phase(Wk_b, bk, k_ws);
  {
    f32x4 acc[4][4];
#pragma unroll
    for (int ci = 0; ci < 4; ++ci)
#pragma unroll
      for (int nb = 0; nb < 4; ++nb) acc[ci][nb] = (f32x4){0.f, 0.f, 0.f, 0.f};
#pragma unroll
    for (int kc = 0; kc < 8; ++kc) {
      bf16x8 bfr[4];
#pragma unroll
      for (int nb = 0; nb < 4; ++nb)
        bfr[nb] = *(const bf16x8*)&T[nb * 16 + l16][kc * 32 + g * 8];
#pragma unroll
      for (int ci = 0; ci < 4; ++ci) {
        const bf16x8 afr = *(const bf16x8*)&Wv_b[((w * 4 + ci) * 16 + l16) * Cc + kc * 32 + g * 8];
#pragma unroll
        for (int nb = 0; nb < 4; ++nb)
          acc[ci][nb] = __builtin_amdgcn_mfma_f32_16x16x32_bf16(afr, bfr[nb], acc[ci][nb], 0, 0, 0);
      }
    }
#pragma unroll
    for (int ci = 0; ci < 4; ++ci) {
#pragma unroll
      for (int r = 0; r < 4; ++r) {
        const int c = (w * 4 + ci) * 16 + g * 4 + r;
        const float bias = bv[c];
#pragma unroll
        for (int nb = 0; nb < 4; ++nb) {
          const int n = n0 + nb * 16 + l16;
          v_ws[(size_t)(b * Cc + c) * Nn + n] = f2b(acc[ci][nb][r] + bias);
        }
      }
    }
  }
}

// ---------------------------------------------------------------------------
// Kernel 3: flash attention — ROUND-7 KERNEL, byte-for-byte (the fastest
// measured variant: 56.4 us). NT=64, single 64-key softmax per tile, no
// skew, no setprio, pairwise reduction trees, 1 barrier/tile. 32x32 MFMA,
// in-register P, rho-permuted K rows, swizzled V LDS via global_load_lds.
// ---------------------------------------------------------------------------
constexpr int NT = 64;
constexpr int VBUF = 256 * NT * 2;   // 32768 B per buffer ([c][8 granules])
constexpr int SBYTES = 2 * VBUF;     // 65536

template <int KS>
__global__ __launch_bounds__(256, 2) void attn_kernel(
    const short* __restrict__ q_ws, const short* __restrict__ k_ws,
    const short* __restrict__ v_ws, short* __restrict__ Opart,
    float* __restrict__ mlm, short* __restrict__ mll) {
  constexpr int KSPAN = Nn / KS;
  constexpr int NTILES = KSPAN / NT;
  __shared__ __align__(16) char smem[SBYTES];
  const int bx = blockIdx.x;
  const int swz = (bx & 7) * (16 * KS) + (bx >> 3);  // XCD-bijective
  const int ks = swz >> 7;
  const int rem = swz & 127;
  const int b = rem >> 5;
  const int m0 = (rem & 31) * 128;
  const int n0 = ks * KSPAN;
  const int tid = threadIdx.x;
  const int w = tid >> 6;
  const int lane = tid & 63;
  const int l31 = lane & 31;
  const int h = lane >> 5;

  // Q B-frags (persist): col m = m0 + w*32 + l31, k = s*16 + 8h + j
  const short* qbase = q_ws + (size_t)(b * Nn + m0 + w * 32 + l31) * Dq + h * 8;
  const bf16x8 qf0 = *(const bf16x8*)(qbase);
  const bf16x8 qf1 = *(const bf16x8*)(qbase + 16);

  // K A-frags at permuted row rho(l31) = swap bits 2<->3 (round-7 verified)
  const int kswap = (l31 & 0x13) | ((l31 & 4) << 1) | ((l31 & 8) >> 1);
  const short* kptr = k_ws + (size_t)(b * Nn + n0 + kswap) * Dq + h * 8;

  // V stage: granule (c = j*32 + tid>>3, slot = tid&7); source pre-swizzled
  // (slot ^= c&7) so the linear LDS-DMA lands the swizzled image.
  const int cth = tid >> 3;
  const int c7 = cth & 7;
  const int koff = 8 * ((tid & 7) ^ c7);
  const short* vsrc[8];
#pragma unroll
  for (int j = 0; j < 8; ++j)
    vsrc[j] = v_ws + (size_t)(b * Cc + j * 32 + cth) * Nn + n0 + koff;

  f32x16 acc[8] = {};  // O[m-pattern reg][c = cb*32 + l31]
  float mrun = -INFINITY, lrun = 0.f;

  // prologue: stage tile 0, prefetch K(0)
#pragma unroll
  for (int j = 0; j < 8; ++j) {
    char* ldst = &smem[(j * 256 + tid) * 16];
    __builtin_amdgcn_global_load_lds(GLB1(vsrc[j]), LDS3(ldst), 16, 0, 0);
    vsrc[j] += NT;
  }
  bf16x8 kf[4];  // [nb*2 + s]
#pragma unroll
  for (int nb = 0; nb < 2; ++nb)
#pragma unroll
    for (int s = 0; s < 2; ++s)
      kf[nb * 2 + s] = *(const bf16x8*)(kptr + nb * 32 * Dq + s * 16);
  kptr += NT * Dq;

  const f32x16 Z = {};
  for (int t = 0; t < NTILES; ++t) {
    const int buf = t & 1;
    // ---- S^T = K*Q^T: lane owns row m = l31; key rows are rho-permuted
    f32x16 sa[2];
    sa[0] = __builtin_amdgcn_mfma_f32_32x32x16_bf16(kf[0], qf0, Z, 0, 0, 0);
    sa[0] = __builtin_amdgcn_mfma_f32_32x32x16_bf16(kf[1], qf1, sa[0], 0, 0, 0);
    sa[1] = __builtin_amdgcn_mfma_f32_32x32x16_bf16(kf[2], qf0, Z, 0, 0, 0);
    sa[1] = __builtin_amdgcn_mfma_f32_32x32x16_bf16(kf[3], qf1, sa[1], 0, 0, 0);

    // ---- wave-local online softmax (lane = one row; partner lane +32)
    float tmax = sa[0][0];
#pragma unroll
    for (int r = 1; r < 16; ++r) tmax = fmaxf(tmax, sa[0][r]);
#pragma unroll
    for (int r = 0; r < 16; ++r) tmax = fmaxf(tmax, sa[1][r]);
    tmax = fmaxf(tmax, __shfl_xor(tmax, 32));
    if (__any(tmax > mrun + 8.f)) {   // defer-max: rescale rarely
      const float mnew = fmaxf(mrun, tmax);
      const float scl = exp2f((mrun - mnew) * L2E);
      float sv[16];
#pragma unroll
      for (int r = 0; r < 16; ++r)
        sv[r] = __shfl(scl, (r & 3) + 8 * (r >> 2) + 4 * h);
#pragma unroll
      for (int cb = 0; cb < 8; ++cb)
#pragma unroll
        for (int r = 0; r < 16; ++r) acc[cb][r] *= sv[r];
      lrun *= scl;
      mrun = mnew;
    }
    const float nml = -mrun * L2E;
    float psum = 0.f;
    unsigned pu[16];
#pragma unroll
    for (int nb = 0; nb < 2; ++nb)
#pragma unroll
      for (int q = 0; q < 8; ++q) {
        const float p0 = exp2f(fmaf(sa[nb][2 * q], L2E, nml));
        const float p1 = exp2f(fmaf(sa[nb][2 * q + 1], L2E, nml));
        psum += p0 + p1;
        pu[nb * 8 + q] = __builtin_amdgcn_perm(fb(p1), fb(p0), 0x07060302u);
      }
    psum += __shfl_xor(psum, 32);
    lrun += psum;

    asm volatile("s_waitcnt vmcnt(0)" ::: "memory");  // V(t) staged
    __syncthreads();

    if (t + 1 < NTILES) {
#pragma unroll
      for (int j = 0; j < 8; ++j) {
        char* ldst = &smem[(buf ^ 1) * VBUF + (j * 256 + tid) * 16];
        __builtin_amdgcn_global_load_lds(GLB1(vsrc[j]), LDS3(ldst), 16, 0, 0);
        vsrc[j] += NT;
      }
#pragma unroll
      for (int nb = 0; nb < 2; ++nb)
#pragma unroll
        for (int s = 0; s < 2; ++s)
          kf[nb * 2 + s] = *(const bf16x8*)(kptr + nb * 32 * Dq + s * 16);
      kptr += NT * Dq;
    }

    // ---- PV: A = pu frags (direct, thanks to rho), B = V[k16][c32] LDS
    const int sb = buf * VBUF;
#pragma unroll
    for (int f = 0; f < 4; ++f) {     // kstep: keys 16f .. 16f+15
      const uint4v au = {pu[4 * f], pu[4 * f + 1], pu[4 * f + 2], pu[4 * f + 3]};
      const bf16x8 A = __builtin_bit_cast(bf16x8, au);
      const char* vbase =
          &smem[sb + l31 * 128 + ((((f << 1) + h) ^ (l31 & 7)) << 4)];
#pragma unroll
      for (int cb = 0; cb < 8; ++cb) {
        const bf16x8 vB = *(const bf16x8*)(vbase + cb * 4096);
        acc[cb] = __builtin_amdgcn_mfma_f32_32x32x16_bf16(A, vB, acc[cb], 0, 0, 0);
      }
    }
  }

  // ---- epilogue: (m,l) + per-wave LDS transpose -> Opart [ks][b][c][m]
  __syncthreads();  // all PV done; smem reusable as transpose strips
  if (h == 0) {
    const int m = m0 + w * 32 + l31;
    mlm[(size_t)(ks * Bc + b) * Nn + m] = mrun;
    mll[(size_t)(ks * Bc + b) * Nn + m] = f2b(lrun);
  }
  char* strip = smem + w * 10240;  // [128 c][80 B] per wave, private
#pragma unroll
  for (int ph = 0; ph < 2; ++ph) {
#pragma unroll
    for (int cb2 = 0; cb2 < 4; ++cb2) {
      const int cb = ph * 4 + cb2;
      const int cs = cb2 * 32 + l31;
#pragma unroll
      for (int q = 0; q < 8; ++q) {   // m-pairs: regs (2q, 2q+1)
        const int mloc = ((2 * q) & 3) + 8 * (q >> 1) + 4 * h;
        const unsigned pv = __builtin_amdgcn_perm(
            fb(acc[cb][2 * q + 1]), fb(acc[cb][2 * q]), 0x07060302u);
        *(unsigned*)(strip + cs * 80 + mloc * 2) = pv;
      }
    }
    asm volatile("s_waitcnt lgkmcnt(0)" ::: "memory");
#pragma unroll
    for (int i = 0; i < 8; ++i) {
      const int gi = i * 64 + lane;
      const int cs = gi >> 2, gq = gi & 3;
      const uint4v vv = *(const uint4v*)(strip + cs * 80 + gq * 16);
      const int cg = ph * 128 + cs;
      const size_t off =
          ((size_t)(ks * Bc + b) * Cc + cg) * Nn + m0 + w * 32 + gq * 8;
      *(uint4v*)&Opart[off] = vv;
    }
    asm volatile("s_waitcnt lgkmcnt(0)" ::: "memory");
  }
}

// ---------------------------------------------------------------------------
// Kernel 4: combine KS key-splits + residual (pure streaming, no transpose).
// ---------------------------------------------------------------------------
template <int KS>
__global__ __launch_bounds__(256) void combine_kernel(
    const short* __restrict__ Opart, const float* __restrict__ mlm,
    const short* __restrict__ mll, const float* __restrict__ feat1,
    const float* __restrict__ gamma_p, float* __restrict__ out) {
  __shared__ float aLDS[KS][64];
  const int bx = blockIdx.x;       // b*64 + mrange
  const int b = bx >> 6;
  const int m0 = (bx & 63) * 64;
  const int tid = threadIdx.x;
  if (tid < 64) {
    const int m = m0 + tid;
    float mm[KS], ll[KS], ms = -INFINITY;
#pragma unroll
    for (int ks = 0; ks < KS; ++ks) {
      mm[ks] = mlm[(size_t)(ks * Bc + b) * Nn + m];
      ll[ks] = b2f(mll[(size_t)(ks * Bc + b) * Nn + m]);
      ms = fmaxf(ms, mm[ks]);
    }
    float es[KS], lsum = 0.f;
#pragma unroll
    for (int ks = 0; ks < KS; ++ks) {
      es[ks] = exp2f((mm[ks] - ms) * L2E);
      lsum += ll[ks] * es[ks];
    }
    const float inv = 1.f / lsum;
#pragma unroll
    for (int ks = 0; ks < KS; ++ks) aLDS[ks][tid] = es[ks] * inv;
  }
  __syncthreads();
  const int mg = tid & 7;          // m-granule (8 m's)
  const int cb = tid >> 3;         // 0..31
  float aks[KS][8];
#pragma unroll
  for (int ks = 0; ks < KS; ++ks)
#pragma unroll
    for (int j = 0; j < 8; ++j) aks[ks][j] = aLDS[ks][mg * 8 + j];
  const float gam = gamma_p[0];
#pragma unroll 2
  for (int i = 0; i < 8; ++i) {
    const int c = cb + i * 32;
    float v[8] = {0.f, 0.f, 0.f, 0.f, 0.f, 0.f, 0.f, 0.f};
#pragma unroll
    for (int ks = 0; ks < KS; ++ks) {
      const bf16x8 ov = *(const bf16x8*)
          &Opart[((size_t)(ks * Bc + b) * Cc + c) * Nn + m0 + mg * 8];
#pragma unroll
      for (int j = 0; j < 8; ++j) v[j] += b2f(ov[j]) * aks[ks][j];
    }
    const size_t base = ((size_t)(b * Cc + c)) * Nn + m0 + mg * 8;
    const f32x4 fa = *(const f32x4*)&feat1[base];
    const f32x4 fbv = *(const f32x4*)&feat1[base + 4];
    f32x4 o0, o1;
#pragma unroll
    for (int j = 0; j < 4; ++j) {
      o0[j] = gam * v[j] + fa[j];
      o1[j] = gam * v[4 + j] + fbv[j];
    }
    *(f32x4*)&out[base] = o0;
    *(f32x4*)&out[base + 4] = o1;
  }
}

// ---------------------------------------------------------------------------
// Launch
// ---------------------------------------------------------------------------
extern "C" void kernel_launch(void* const* d_in, const int* in_sizes, int n_in,
                              void* d_out, int out_size, void* d_ws,
                              size_t ws_size, hipStream_t stream) {
  const float* feat1 = (const float*)d_in[0];
  const float* feat2 = (const float*)d_in[1];
  const float* Wq = (const float*)d_in[2];
  const float* bq = (const float*)d_in[3];
  const float* Wk = (const float*)d_in[4];
  const float* bk = (const float*)d_in[5];
  const float* Wv = (const float*)d_in[6];
  const float* bv = (const float*)d_in[7];
  const float* gamma = (const float*)d_in[8];
  float* out = (float*)d_out;
  char* ws = (char*)d_ws;

  const size_t need4 = 44433408;  // proven ws >= 44466176 (round-5 KS=2 ran)
  if (ws_size >= need4) {
    // KS=4 layout. Weights overlay Opart (consumed before attn writes it).
    short* Opart = (short*)(ws + 0);          // 32 MiB [4][4][256][4096] bf16
    short* Wq_b = (short*)(ws + 16777216);    // 16 KiB (overlay)
    short* Wk_b = (short*)(ws + 16793600);
    short* Wv_b = (short*)(ws + 16809984);    // 128 KiB (overlay)
    short* q_ws = (short*)(ws + 33554432);    // 1 MiB
    short* k_ws = (short*)(ws + 34603008);    // 1 MiB
    short* v_ws = (short*)(ws + 35651584);    // 8 MiB
    float* mlm  = (float*)(ws + 44040192);    // 256 KiB f32
    short* mll  = (short*)(ws + 44302336);    // 128 KiB bf16

    prep_weights<<<80, 256, 0, stream>>>(Wq, Wk, Wv, Wq_b, Wk_b, Wv_b);
    proj_fused<<<256, 256, 0, stream>>>(feat1, feat2, Wq_b, bq, Wk_b, bk,
                                        Wv_b, bv, q_ws, k_ws, v_ws);
    attn_kernel<4><<<512, 256, 0, stream>>>(q_ws, k_ws, v_ws, Opart, mlm, mll);
    combine_kernel<4><<<256, 256, 0, stream>>>(Opart, mlm, mll, feat1, gamma,
                                               out);
  } else {
    // KS=2 fallback (~27.7 MiB).
    short* Opart = (short*)(ws + 0);          // 16 MiB
    short* Wq_b = (short*)(ws + 16777216);
    short* Wk_b = (short*)(ws + 16793600);
    short* Wv_b = (short*)(ws + 16809984);
    short* q_ws = (short*)(ws + 16941056);
    short* k_ws = (short*)(ws + 17989632);
    short* v_ws = (short*)(ws + 19038208);
    float* mlm  = (float*)(ws + 27426816);
    short* mll  = (short*)(ws + 27557888);

    prep_weights<<<80, 256, 0, stream>>>(Wq, Wk, Wv, Wq_b, Wk_b, Wv_b);
    proj_fused<<<256, 256, 0, stream>>>(feat1, feat2, Wq_b, bq, Wk_b, bk,
                                        Wv_b, bv, q_ws, k_ws, v_ws);
    attn_kernel<2><<<256, 256, 0, stream>>>(q_ws, k_ws, v_ws, Opart, mlm, mll);
    combine_kernel<2><<<256, 256, 0, stream>>>(Opart, mlm, mll, feat1, gamma,
                                               out);
  }
}